// Round 4
// baseline (723.601 us; speedup 1.0000x reference)
//
#include <hip/hip_runtime.h>
#include <hip/hip_bf16.h>

// Problem constants
#define BB 8
#define MELN 64
#define TSN 512
#define HHN 128
#define CCN 20

// ws layout (float offsets)
#define OFF_WINT  0                          // W_in^T [64][128]
#define OFF_WT    8192                       // 10x [128][128] transposed: ii,if,ig,io,xo,q,hi,hf,hg,ho
#define OFF_RS    (OFF_WT + 10*16384)        // [128][4] rowsums of W_hi,W_hf,W_hg,W_ho
#define OFF_XPRE  (OFF_RS + 512)             // [B][T][128 rows][4 gates] x-terms (+both biases) f32
#define OFF_AQ    (OFF_XPRE + BB*TSN*512)    // [B][T][128] a = q/sqrt(H) f32
#define OFF_HALL  (OFF_AQ + BB*TSN*128)      // [B][T][128] h_t f32
#define OFF_APRE  (OFF_HALL + BB*TSN*128)    // [B][T][128] uint4: 4x pk2(A1_g, A2_g) f16, A_p = W_hg @ a^p
// total floats = OFF_APRE + BB*TSN*128*2 = 5,415,424 (~20.7 MB)

typedef _Float16 hf2 __attribute__((ext_vector_type(2)));

__device__ __forceinline__ float rcp_f(float x) { return __builtin_amdgcn_rcpf(x); }
__device__ __forceinline__ float sigm_f(float x) { return rcp_f(1.0f + __expf(-x)); }
__device__ __forceinline__ float tanh_f(float x) { return fmaf(2.0f, rcp_f(1.0f + __expf(-2.0f * x)), -1.0f); }
__device__ __forceinline__ float sigm_p(float x) { return 1.0f / (1.0f + __expf(-x)); }

#if __has_builtin(__builtin_amdgcn_fdot2)
__device__ __forceinline__ float dot2f(hf2 a, hf2 b, float c) {
  return __builtin_amdgcn_fdot2(a, b, c, false);
}
#else
__device__ __forceinline__ float dot2f(hf2 a, hf2 b, float c) {
  return fmaf((float)a.x, (float)b.x, fmaf((float)a.y, (float)b.y, c));
}
#endif

__device__ __forceinline__ hf2 mk2(float a, float b) {
  hf2 v; v.x = (_Float16)a; v.y = (_Float16)b; return v;
}
__device__ __forceinline__ unsigned pk2(float a, float b) {
  return __builtin_bit_cast(unsigned, __builtin_amdgcn_cvt_pkrtz(a, b));
}
__device__ __forceinline__ hf2 u2h(unsigned u) { return __builtin_bit_cast(hf2, u); }

// ---- wave-64 sum: DPP (VALU-pipe) with shfl fallback. Result valid in lane 63. ----
#if __has_builtin(__builtin_amdgcn_update_dpp)
template <int CTRL>
__device__ __forceinline__ float dppadd(float x) {
  int v = __builtin_amdgcn_update_dpp(0, __builtin_bit_cast(int, x), CTRL, 0xf, 0xf, true);
  return x + __builtin_bit_cast(float, v);
}
__device__ __forceinline__ float wsum64(float x) {
  x = dppadd<0x111>(x);   // row_shr:1
  x = dppadd<0x112>(x);   // row_shr:2
  x = dppadd<0x114>(x);   // row_shr:4
  x = dppadd<0x118>(x);   // row_shr:8  -> lane15 of each 16-row has row sum
  x = dppadd<0x142>(x);   // row_bcast:15 -> lane31/63 have 32-lane sums
  x = dppadd<0x143>(x);   // row_bcast:31 -> lane63 has 64-lane sum
  return x;
}
#else
__device__ __forceinline__ float wsum64(float x) {
  x += __shfl_xor(x, 1);  x += __shfl_xor(x, 2);  x += __shfl_xor(x, 4);
  x += __shfl_xor(x, 8);  x += __shfl_xor(x, 16); x += __shfl_xor(x, 32);
  return x;
}
#endif

// ---- lgkm-only workgroup barrier: does NOT drain vmcnt, so in-flight global
// prefetch loads survive across it. Only LDS needs cross-wave visibility.
__device__ __forceinline__ void ldsbar() {
  __builtin_amdgcn_sched_barrier(0);
  asm volatile("s_waitcnt lgkmcnt(0)" ::: "memory");
  __builtin_amdgcn_s_barrier();
  __builtin_amdgcn_sched_barrier(0);
}

// ---------------- P0: transpose weights + rowsums ----------------
__global__ void k_prep(const float* __restrict__ W_in, const float* __restrict__ W_ii,
                       const float* __restrict__ W_if, const float* __restrict__ W_ig,
                       const float* __restrict__ W_io, const float* __restrict__ W_xo,
                       const float* __restrict__ W_q,  const float* __restrict__ W_hi,
                       const float* __restrict__ W_hf, const float* __restrict__ W_hg,
                       const float* __restrict__ W_ho, float* __restrict__ ws) {
  int m = blockIdx.x;  // 0..11
  if (m == 11) {
    for (int idx = threadIdx.x; idx < 512; idx += blockDim.x) {
      int g = idx >> 7, r = idx & 127;
      const float* W = (g == 0) ? W_hi : (g == 1) ? W_hf : (g == 2) ? W_hg : W_ho;
      float s = 0.f;
      for (int c = 0; c < 128; ++c) s += W[r * 128 + c];
      ws[OFF_RS + r * 4 + g] = s;
    }
    return;
  }
  const float* src;
  float* dst;
  int C;
  if (m == 0) { src = W_in; dst = ws + OFF_WINT; C = 64; }
  else {
    const float* s[10] = {W_ii, W_if, W_ig, W_io, W_xo, W_q, W_hi, W_hf, W_hg, W_ho};
    src = s[m - 1];
    dst = ws + OFF_WT + (size_t)(m - 1) * 16384;
    C = 128;
  }
  int n = 128 * C;
  for (int idx = threadIdx.x; idx < n; idx += blockDim.x) {
    int r = idx / C, c = idx - r * C;
    dst[c * 128 + r] = src[idx];   // dst[c][r] = W[r][c]
  }
}

// ---------------- P1: x-side projections + A-moment precompute, 8 t's per block ----------------
__global__ __launch_bounds__(128)
void k_xproj(const float* __restrict__ x,
             const float* __restrict__ b_in,
             const float* __restrict__ b_ii, const float* __restrict__ b_hi,
             const float* __restrict__ b_if, const float* __restrict__ b_hf,
             const float* __restrict__ b_ig, const float* __restrict__ b_hg,
             const float* __restrict__ b_io, const float* __restrict__ b_ho,
             const float* __restrict__ b_xo, const float* __restrict__ b_q,
             float* __restrict__ ws) {
  const int tid = threadIdx.x;
  const int b  = blockIdx.x >> 6;
  const int t0 = (blockIdx.x & 63) * 8;

  __shared__ __align__(16) float xsT[MELN * 8];   // [m][tt]
  __shared__ __align__(16) float xpsT[128 * 8];   // [c][tt]   (reused for a, a^2)
  __shared__ __align__(16) float xosT[128 * 8];   // [c][tt]

  const float* WinT = ws + OFF_WINT;
  const float* WT   = ws + OFF_WT;
  float* Xpre = ws + OFF_XPRE;
  float* aq   = ws + OFF_AQ;

  #pragma unroll
  for (int k = 0; k < 4; ++k) {
    int mm = k * 16 + (tid >> 3);
    int tt = tid & 7;
    xsT[mm * 8 + tt] = x[((size_t)b * MELN + mm) * TSN + t0 + tt];
  }
  __syncthreads();

  // xp rows: thread = output feature
  float acc8[8];
  {
    float bi = b_in[tid];
    #pragma unroll
    for (int j = 0; j < 8; ++j) acc8[j] = bi;
  }
  for (int mI = 0; mI < MELN; ++mI) {
    float w = WinT[mI * 128 + tid];
    float4 xa = *(const float4*)&xsT[mI * 8];
    float4 xb = *(const float4*)&xsT[mI * 8 + 4];
    acc8[0] = fmaf(w, xa.x, acc8[0]); acc8[1] = fmaf(w, xa.y, acc8[1]);
    acc8[2] = fmaf(w, xa.z, acc8[2]); acc8[3] = fmaf(w, xa.w, acc8[3]);
    acc8[4] = fmaf(w, xb.x, acc8[4]); acc8[5] = fmaf(w, xb.y, acc8[5]);
    acc8[6] = fmaf(w, xb.z, acc8[6]); acc8[7] = fmaf(w, xb.w, acc8[7]);
  }
  *(float4*)&xpsT[tid * 8]     = make_float4(acc8[0], acc8[1], acc8[2], acc8[3]);
  *(float4*)&xpsT[tid * 8 + 4] = make_float4(acc8[4], acc8[5], acc8[6], acc8[7]);
  __syncthreads();

  // gate x-terms (ii,if,ig,io) + xo
  float accg[5][8];
  {
    float bsum[5];
    bsum[0] = b_ii[tid] + b_hi[tid];
    bsum[1] = b_if[tid] + b_hf[tid];
    bsum[2] = b_ig[tid] + b_hg[tid];
    bsum[3] = b_io[tid] + b_ho[tid];
    bsum[4] = b_xo[tid];
    #pragma unroll
    for (int g = 0; g < 5; ++g)
      #pragma unroll
      for (int j = 0; j < 8; ++j) accg[g][j] = bsum[g];
  }
  for (int c = 0; c < 128; ++c) {
    const float4 xa = *(const float4*)&xpsT[c * 8];
    const float4 xb = *(const float4*)&xpsT[c * 8 + 4];
    #pragma unroll
    for (int g = 0; g < 5; ++g) {
      const float w = WT[g * 16384 + c * 128 + tid];
      accg[g][0] = fmaf(w, xa.x, accg[g][0]);
      accg[g][1] = fmaf(w, xa.y, accg[g][1]);
      accg[g][2] = fmaf(w, xa.z, accg[g][2]);
      accg[g][3] = fmaf(w, xa.w, accg[g][3]);
      accg[g][4] = fmaf(w, xb.x, accg[g][4]);
      accg[g][5] = fmaf(w, xb.y, accg[g][5]);
      accg[g][6] = fmaf(w, xb.z, accg[g][6]);
      accg[g][7] = fmaf(w, xb.w, accg[g][7]);
    }
  }
  {
    size_t base = ((size_t)b * TSN + t0) * 512;
    #pragma unroll
    for (int tt = 0; tt < 8; ++tt)
      *(float4*)&Xpre[base + (size_t)tt * 512 + tid * 4] =
          make_float4(accg[0][tt], accg[1][tt], accg[2][tt], accg[3][tt]);
  }
  {
    #pragma unroll
    for (int tt = 0; tt < 8; ++tt) xosT[tid * 8 + tt] = sigm_p(accg[4][tt]);
  }
  __syncthreads();

  // q projection on x_o -> a = q / sqrt(H)
  float accq[8];
  {
    float bq = b_q[tid];
    #pragma unroll
    for (int j = 0; j < 8; ++j) accq[j] = bq;
  }
  for (int c = 0; c < 128; ++c) {
    const float w = WT[5 * 16384 + c * 128 + tid];
    const float4 xa = *(const float4*)&xosT[c * 8];
    const float4 xb = *(const float4*)&xosT[c * 8 + 4];
    accq[0] = fmaf(w, xa.x, accq[0]); accq[1] = fmaf(w, xa.y, accq[1]);
    accq[2] = fmaf(w, xa.z, accq[2]); accq[3] = fmaf(w, xa.w, accq[3]);
    accq[4] = fmaf(w, xb.x, accq[4]); accq[5] = fmaf(w, xb.y, accq[5]);
    accq[6] = fmaf(w, xb.z, accq[6]); accq[7] = fmaf(w, xb.w, accq[7]);
  }
  float av[8];
  #pragma unroll
  for (int tt = 0; tt < 8; ++tt) {
    av[tt] = accq[tt] * 0.08838834764831845f;
    aq[((size_t)b * TSN + t0 + tt) * 128 + tid] = av[tt];
  }

  // ---- A-moment precompute: A1 = W_hg @ a, A2 = W_hg @ a^2 (4 gates), stored f16 pairs ----
  __syncthreads();
  *(float4*)&xpsT[tid * 8]     = make_float4(av[0], av[1], av[2], av[3]);
  *(float4*)&xpsT[tid * 8 + 4] = make_float4(av[4], av[5], av[6], av[7]);
  __syncthreads();
  float accA[4][8];
  #pragma unroll
  for (int g = 0; g < 4; ++g)
    #pragma unroll
    for (int j = 0; j < 8; ++j) accA[g][j] = 0.f;
  for (int c = 0; c < 128; ++c) {
    const float4 xa = *(const float4*)&xpsT[c * 8];
    const float4 xb = *(const float4*)&xpsT[c * 8 + 4];
    #pragma unroll
    for (int g = 0; g < 4; ++g) {
      const float w = WT[(6 + g) * 16384 + c * 128 + tid];
      accA[g][0] = fmaf(w, xa.x, accA[g][0]);
      accA[g][1] = fmaf(w, xa.y, accA[g][1]);
      accA[g][2] = fmaf(w, xa.z, accA[g][2]);
      accA[g][3] = fmaf(w, xa.w, accA[g][3]);
      accA[g][4] = fmaf(w, xb.x, accA[g][4]);
      accA[g][5] = fmaf(w, xb.y, accA[g][5]);
      accA[g][6] = fmaf(w, xb.z, accA[g][6]);
      accA[g][7] = fmaf(w, xb.w, accA[g][7]);
    }
  }
  __syncthreads();
  *(float4*)&xpsT[tid * 8]     = make_float4(av[0]*av[0], av[1]*av[1], av[2]*av[2], av[3]*av[3]);
  *(float4*)&xpsT[tid * 8 + 4] = make_float4(av[4]*av[4], av[5]*av[5], av[6]*av[6], av[7]*av[7]);
  __syncthreads();
  float accB[4][8];
  #pragma unroll
  for (int g = 0; g < 4; ++g)
    #pragma unroll
    for (int j = 0; j < 8; ++j) accB[g][j] = 0.f;
  for (int c = 0; c < 128; ++c) {
    const float4 xa = *(const float4*)&xpsT[c * 8];
    const float4 xb = *(const float4*)&xpsT[c * 8 + 4];
    #pragma unroll
    for (int g = 0; g < 4; ++g) {
      const float w = WT[(6 + g) * 16384 + c * 128 + tid];
      accB[g][0] = fmaf(w, xa.x, accB[g][0]);
      accB[g][1] = fmaf(w, xa.y, accB[g][1]);
      accB[g][2] = fmaf(w, xa.z, accB[g][2]);
      accB[g][3] = fmaf(w, xa.w, accB[g][3]);
      accB[g][4] = fmaf(w, xb.x, accB[g][4]);
      accB[g][5] = fmaf(w, xb.y, accB[g][5]);
      accB[g][6] = fmaf(w, xb.z, accB[g][6]);
      accB[g][7] = fmaf(w, xb.w, accB[g][7]);
    }
  }
  {
    uint4* APre4 = (uint4*)(ws + OFF_APRE);
    #pragma unroll
    for (int tt = 0; tt < 8; ++tt) {
      uint4 u;
      u.x = pk2(accA[0][tt], accB[0][tt]);
      u.y = pk2(accA[1][tt], accB[1][tt]);
      u.z = pk2(accA[2][tt], accB[2][tt]);
      u.w = pk2(accA[3][tt], accB[3][tt]);
      APre4[((size_t)b * TSN + t0 + tt) * 128 + tid] = u;
    }
  }
}

// ---------------- P2: scan. 2 waves, TWO independent batches interleaved per block.
// Each batch's stall windows (LDS round-trip, DPP chains, exp/rcp latency) are
// filled by the other batch's independent instructions. Barriers shared. ----
__global__ __launch_bounds__(128, 1)
void k_scan(const float* __restrict__ W_k,  const float* __restrict__ b_k,
            const float* __restrict__ W_v,  const float* __restrict__ b_v,
            const float* __restrict__ W_ao, const float* __restrict__ b_ao,
            float* __restrict__ ws) {
  const int tid  = threadIdx.x;    // row 0..127
  const int lane = tid & 63;
  const int wid  = tid >> 6;       // wave 0..1
  const int b0   = 2 * blockIdx.x;
  const int b1   = b0 + 1;

  __shared__ __align__(16) _Float16 ch0[128];    // c (batch0) as f16
  __shared__ __align__(16) _Float16 ch1[128];    // c (batch1) as f16
  __shared__ __align__(16) float part[32];       // [batch][wave][moment] stride 8

  // full W_k row in registers as 64 f16 pairs (64 VGPRs) — shared by both batches
  hf2 wkk2[64];
  #pragma unroll
  for (int p = 0; p < 64; ++p)
    wkk2[p] = mk2(W_k[(size_t)tid * 128 + 2 * p], W_k[(size_t)tid * 128 + 2 * p + 1]);
  const float bkr = b_k[tid];
  const float4 RSv = *(const float4*)&ws[OFF_RS + tid * 4];   // rowsums (ii,if,ig,io)

  // collapsed attention-output constants: h = s1*(attn.o) + s2
  float s1 = 0.f, s2 = 0.f;
  for (int j = 0; j < 128; ++j) {
    s1 = fmaf(W_ao[j], W_v[j], s1);
    s2 = fmaf(W_ao[j], b_v[j], s2);
  }
  s2 += b_ao[0];
  const float inv128 = 0.0078125f;
  const float s1i = s1 * inv128;

  const float* Xb0 = ws + OFF_XPRE + (size_t)b0 * TSN * 512;
  const float* Xb1 = ws + OFF_XPRE + (size_t)b1 * TSN * 512;
  const float* ab0 = ws + OFF_AQ   + (size_t)b0 * TSN * 128;
  const float* ab1 = ws + OFF_AQ   + (size_t)b1 * TSN * 128;
  float*       Hb0 = ws + OFF_HALL + (size_t)b0 * TSN * 128;
  float*       Hb1 = ws + OFF_HALL + (size_t)b1 * TSN * 128;
  const uint4* APb0 = (const uint4*)(ws + OFF_APRE) + (size_t)b0 * TSN * 128;
  const uint4* APb1 = (const uint4*)(ws + OFF_APRE) + (size_t)b1 * TSN * 128;

  const uint4* c4u0 = (const uint4*)ch0;
  const uint4* c4u1 = (const uint4*)ch1;

  // even/odd register sets per batch (distance-2 prefetch; static names, rule #20)
  float4 X4e0 = *(const float4*)&Xb0[tid * 4];
  float4 X4o0 = *(const float4*)&Xb0[512 + tid * 4];
  float4 X4e1 = *(const float4*)&Xb1[tid * 4];
  float4 X4o1 = *(const float4*)&Xb1[512 + tid * 4];
  float  are0 = ab0[tid];
  float  aro0 = ab0[128 + tid];
  float  are1 = ab1[tid];
  float  aro1 = ab1[128 + tid];
  uint4  Ae0  = APb0[tid], Ao0 = APb0[tid];   // dummy finite at t=0 (gamma=0)
  uint4  Ae1  = APb1[tid], Ao1 = APb1[tid];

  float c_0 = 0.f, c_1 = 0.f;
  float g0a = 0.f, g0b = 0.f;            // gamma0 per batch
  hf2   g12a = u2h(0u), g12b = u2h(0u);  // (gamma1, gamma2) f16 per batch

  // deferred-h state per batch
  float g0pa = 0.f, gm1pa = 0.f, gm2pa = 0.f, arpa = 0.f;
  float g0pb = 0.f, gm1pb = 0.f, gm2pb = 0.f, arpb = 0.f;

// One scan step for BOTH batches, instruction streams interleaved.
#define SCAN_STEP(T, X4v0, arv0, A0v, X4v1, arv1, A1v)                        \
  {                                                                           \
    /* gates i/f/g both batches */                                            \
    const float pi0 = dot2f(u2h((A0v).x), g12a, fmaf(g0a, RSv.x, (X4v0).x));  \
    const float pi1 = dot2f(u2h((A1v).x), g12b, fmaf(g0b, RSv.x, (X4v1).x));  \
    const float pf0 = dot2f(u2h((A0v).y), g12a, fmaf(g0a, RSv.y, (X4v0).y));  \
    const float pf1 = dot2f(u2h((A1v).y), g12b, fmaf(g0b, RSv.y, (X4v1).y));  \
    const float pg0 = dot2f(u2h((A0v).z), g12a, fmaf(g0a, RSv.z, (X4v0).z));  \
    const float pg1 = dot2f(u2h((A1v).z), g12b, fmaf(g0b, RSv.z, (X4v1).z));  \
    const float gi0 = sigm_f(pi0), gi1 = sigm_f(pi1);                         \
    const float gf0 = sigm_f(pf0), gf1 = sigm_f(pf1);                         \
    const float gg0 = tanh_f(pg0), gg1 = tanh_f(pg1);                         \
    c_0 = fmaf(gf0, c_0, gi0 * gg0);                                          \
    c_1 = fmaf(gf1, c_1, gi1 * gg1);                                          \
    ch0[tid] = (_Float16)c_0;                                                 \
    ch1[tid] = (_Float16)c_1;                                                 \
    /* gap fill: o-gates, prefetches, deferred h stores (both batches) */     \
    const float po0 = dot2f(u2h((A0v).w), g12a, fmaf(g0a, RSv.w, (X4v0).w));  \
    const float po1 = dot2f(u2h((A1v).w), g12b, fmaf(g0b, RSv.w, (X4v1).w));  \
    const float go0 = sigm_f(po0), go1 = sigm_f(po1);                         \
    {                                                                         \
      const int tx = ((T) + 2 < TSN) ? (T) + 2 : TSN - 1;                     \
      (X4v0) = *(const float4*)&Xb0[(size_t)tx * 512 + tid * 4];              \
      (X4v1) = *(const float4*)&Xb1[(size_t)tx * 512 + tid * 4];              \
      const int ta = ((T) + 1 < TSN) ? (T) + 1 : TSN - 1;                     \
      (A0v) = APb0[(size_t)ta * 128 + tid];                                   \
      (A1v) = APb1[(size_t)ta * 128 + tid];                                   \
    }                                                                         \
    {                                                                         \
      int th = (T) - 1; th = th < 0 ? 0 : th;                                 \
      Hb0[(size_t)th * 128 + tid] = fmaf(fmaf(gm2pa, arpa, gm1pa), arpa, g0pa); \
      Hb1[(size_t)th * 128 + tid] = fmaf(fmaf(gm2pb, arpb, gm1pb), arpb, g0pb); \
    }                                                                         \
    ldsbar();  /* [1] c visible (lgkm-only) */                                \
    float ka0 = 0.f, ka1 = 0.f, ka2 = 0.f, ka3 = 0.f;                         \
    float ka4 = 0.f, ka5 = 0.f, ka6 = 0.f, ka7 = 0.f;                         \
    float kb0 = 0.f, kb1 = 0.f, kb2 = 0.f, kb3 = 0.f;                         \
    float kb4 = 0.f, kb5 = 0.f, kb6 = 0.f, kb7 = 0.f;                         \
    _Pragma("unroll")                                                         \
    for (int u = 0; u < 8; ++u) {                                             \
      const uint4 cv00 = c4u0[2 * u];                                         \
      const uint4 cv01 = c4u0[2 * u + 1];                                     \
      const uint4 cv10 = c4u1[2 * u];                                         \
      const uint4 cv11 = c4u1[2 * u + 1];                                     \
      ka0 = dot2f(wkk2[u * 8 + 0], u2h(cv00.x), ka0);                         \
      ka1 = dot2f(wkk2[u * 8 + 1], u2h(cv00.y), ka1);                         \
      ka2 = dot2f(wkk2[u * 8 + 2], u2h(cv00.z), ka2);                         \
      ka3 = dot2f(wkk2[u * 8 + 3], u2h(cv00.w), ka3);                         \
      kb0 = dot2f(wkk2[u * 8 + 0], u2h(cv10.x), kb0);                         \
      kb1 = dot2f(wkk2[u * 8 + 1], u2h(cv10.y), kb1);                         \
      kb2 = dot2f(wkk2[u * 8 + 2], u2h(cv10.z), kb2);                         \
      kb3 = dot2f(wkk2[u * 8 + 3], u2h(cv10.w), kb3);                         \
      ka4 = dot2f(wkk2[u * 8 + 4], u2h(cv01.x), ka4);                         \
      ka5 = dot2f(wkk2[u * 8 + 5], u2h(cv01.y), ka5);                         \
      ka6 = dot2f(wkk2[u * 8 + 6], u2h(cv01.z), ka6);                         \
      ka7 = dot2f(wkk2[u * 8 + 7], u2h(cv01.w), ka7);                         \
      kb4 = dot2f(wkk2[u * 8 + 4], u2h(cv11.x), kb4);                         \
      kb5 = dot2f(wkk2[u * 8 + 5], u2h(cv11.y), kb5);                         \
      kb6 = dot2f(wkk2[u * 8 + 6], u2h(cv11.z), kb6);                         \
      kb7 = dot2f(wkk2[u * 8 + 7], u2h(cv11.w), kb7);                         \
    }                                                                         \
    const float kr0 = (((ka0 + ka1) + (ka2 + ka3)) +                          \
                       ((ka4 + ka5) + (ka6 + ka7))) + bkr;                    \
    const float kr1 = (((kb0 + kb1) + (kb2 + kb3)) +                          \
                       ((kb4 + kb5) + (kb6 + kb7))) + bkr;                    \
    const float kp0 = kr0 * kr0, kp1 = kr1 * kr1;                             \
    float m00 = kr0, m01 = go0, m02 = kp0, m03 = go0 * kr0, m04 = go0 * kp0;  \
    float m10 = kr1, m11 = go1, m12 = kp1, m13 = go1 * kr1, m14 = go1 * kp1;  \
    m00 = wsum64(m00); m10 = wsum64(m10);                                     \
    m01 = wsum64(m01); m11 = wsum64(m11);                                     \
    m02 = wsum64(m02); m12 = wsum64(m12);                                     \
    m03 = wsum64(m03); m13 = wsum64(m13);                                     \
    m04 = wsum64(m04); m14 = wsum64(m14);                                     \
    if (lane == 63) {                                                         \
      *(float4*)&part[wid * 8] = make_float4(m00, m01, m02, m03);             \
      part[wid * 8 + 4] = m04;                                                \
      *(float4*)&part[16 + wid * 8] = make_float4(m10, m11, m12, m13);        \
      part[16 + wid * 8 + 4] = m14;                                           \
    }                                                                         \
    /* gap fill: save ar for deferred h, prefetch ar(T+2) (both) */           \
    arpa = (arv0); arpb = (arv1);                                             \
    {                                                                         \
      const int tr = ((T) + 2 < TSN) ? (T) + 2 : TSN - 1;                     \
      (arv0) = ab0[(size_t)tr * 128 + tid];                                   \
      (arv1) = ab1[(size_t)tr * 128 + tid];                                   \
    }                                                                         \
    ldsbar();  /* [2] partials visible (lgkm-only) */                         \
    {                                                                         \
      const float4 pa = *(const float4*)&part[0];                             \
      const float4 pb = *(const float4*)&part[8];                             \
      const float D1 = pa.x + pb.x;                                           \
      const float N0 = pa.y + pb.y;                                           \
      const float D2 = pa.z + pb.z;                                           \
      const float N1 = pa.w + pb.w;                                           \
      const float N2 = part[4] + part[12];                                    \
      const float t1 = D1 * inv128;                                           \
      g0a = fmaf(s1i, N0, s2);                                                \
      const float gm1 = s1i * (N1 - N0 * t1);                                 \
      const float gm2 = s1i * (0.5f * N2 - (N1 * D1 + 0.5f * N0 * D2) * inv128 \
                               + N0 * t1 * t1);                               \
      g12a = u2h(pk2(gm1, gm2));                                              \
      g0pa = g0a; gm1pa = gm1; gm2pa = gm2;                                   \
    }                                                                         \
    {                                                                         \
      const float4 pa = *(const float4*)&part[16];                            \
      const float4 pb = *(const float4*)&part[24];                            \
      const float D1 = pa.x + pb.x;                                           \
      const float N0 = pa.y + pb.y;                                           \
      const float D2 = pa.z + pb.z;                                           \
      const float N1 = pa.w + pb.w;                                           \
      const float N2 = part[20] + part[28];                                   \
      const float t1 = D1 * inv128;                                           \
      g0b = fmaf(s1i, N0, s2);                                                \
      const float gm1 = s1i * (N1 - N0 * t1);                                 \
      const float gm2 = s1i * (0.5f * N2 - (N1 * D1 + 0.5f * N0 * D2) * inv128 \
                               + N0 * t1 * t1);                               \
      g12b = u2h(pk2(gm1, gm2));                                              \
      g0pb = g0b; gm1pb = gm1; gm2pb = gm2;                                   \
    }                                                                         \
  }

  for (int k = 0; k < TSN / 2; ++k) {
    SCAN_STEP(2 * k,     X4e0, are0, Ae0, X4e1, are1, Ae1);
    SCAN_STEP(2 * k + 1, X4o0, aro0, Ao0, X4o1, aro1, Ao1);
  }
#undef SCAN_STEP

  // epilogue: h for T = 511, both batches
  Hb0[(size_t)(TSN - 1) * 128 + tid] = fmaf(fmaf(gm2pa, arpa, gm1pa), arpa, g0pa);
  Hb1[(size_t)(TSN - 1) * 128 + tid] = fmaf(fmaf(gm2pb, arpb, gm1pb), arpb, g0pb);
}

// ---------------- P3: y = Hall @ W_out^T + b_out -> fp32 (B,C,T) ----------------
__global__ __launch_bounds__(256)
void k_out(const float* __restrict__ W_out, const float* __restrict__ b_out,
           const float* __restrict__ ws, float* __restrict__ out) {
  const int tid = threadIdx.x;
  const int b  = blockIdx.x >> 3;
  const int t0 = (blockIdx.x & 7) * 64;

  __shared__ __align__(16) float Hs[64 * 136];  // padded stride

  const float* Hb = ws + OFF_HALL + ((size_t)b * TSN + t0) * 128;
  for (int k = 0; k < 32; ++k) {
    const int idx = k * 256 + tid;
    Hs[(idx >> 7) * 136 + (idx & 127)] = Hb[idx];
  }
  __syncthreads();

  const int tt = tid & 63;
  const int c0 = (tid >> 6) * 5;
  for (int j = 0; j < 5; ++j) {
    const int c = c0 + j;
    float s = b_out[c];
    for (int i = 0; i < 128; ++i)
      s = fmaf(Hs[tt * 136 + i], W_out[c * 128 + i], s);
    out[((size_t)b * CCN + c) * TSN + t0 + tt] = s;
  }
}

extern "C" void kernel_launch(void* const* d_in, const int* in_sizes, int n_in,
                              void* d_out, int out_size, void* d_ws, size_t ws_size,
                              hipStream_t stream) {
  const float* x    = (const float*)d_in[0];
  const float* W_in = (const float*)d_in[1];
  const float* b_in = (const float*)d_in[2];
  const float* W_out= (const float*)d_in[3];
  const float* b_out= (const float*)d_in[4];
  const float* W_ii = (const float*)d_in[5];
  const float* b_ii = (const float*)d_in[6];
  const float* W_hi = (const float*)d_in[7];
  const float* b_hi = (const float*)d_in[8];
  const float* W_if = (const float*)d_in[9];
  const float* b_if = (const float*)d_in[10];
  const float* W_hf = (const float*)d_in[11];
  const float* b_hf = (const float*)d_in[12];
  const float* W_ig = (const float*)d_in[13];
  const float* b_ig = (const float*)d_in[14];
  const float* W_hg = (const float*)d_in[15];
  const float* b_hg = (const float*)d_in[16];
  const float* W_io = (const float*)d_in[17];
  const float* b_io = (const float*)d_in[18];
  const float* W_ho = (const float*)d_in[19];
  const float* b_ho = (const float*)d_in[20];
  const float* W_xo = (const float*)d_in[21];
  const float* b_xo = (const float*)d_in[22];
  const float* W_q  = (const float*)d_in[23];
  const float* b_q  = (const float*)d_in[24];
  const float* W_k  = (const float*)d_in[25];
  const float* b_k  = (const float*)d_in[26];
  const float* W_v  = (const float*)d_in[27];
  const float* b_v  = (const float*)d_in[28];
  const float* W_ao = (const float*)d_in[29];
  const float* b_ao = (const float*)d_in[30];

  float* ws = (float*)d_ws;
  float* out = (float*)d_out;

  k_prep<<<12, 256, 0, stream>>>(W_in, W_ii, W_if, W_ig, W_io, W_xo, W_q,
                                 W_hi, W_hf, W_hg, W_ho, ws);
  k_xproj<<<512, 128, 0, stream>>>(x, b_in, b_ii, b_hi, b_if, b_hf, b_ig, b_hg,
                                   b_io, b_ho, b_xo, b_q, ws);
  k_scan<<<BB / 2, 128, 0, stream>>>(W_k, b_k, W_v, b_v, W_ao, b_ao, ws);
  k_out<<<BB * 8, 256, 0, stream>>>(W_out, b_out, ws, out);
}

// Round 5
// 478.362 us; speedup vs baseline: 1.5127x; 1.5127x over previous
//
#include <hip/hip_runtime.h>
#include <hip/hip_bf16.h>

// Problem constants
#define BB 8
#define MELN 64
#define TSN 512
#define HHN 128
#define CCN 20

// ws layout (float offsets)
#define OFF_WINT  0                          // W_in^T [64][128]
#define OFF_WT    8192                       // 10x [128][128] transposed: ii,if,ig,io,xo,q,hi,hf,hg,ho
#define OFF_RS    (OFF_WT + 10*16384)        // [128][4] rowsums of W_hi,W_hf,W_hg,W_ho
#define OFF_XPRE  (OFF_RS + 512)             // [B][T][128 rows][4 gates] x-terms (+both biases) f32
#define OFF_AQ    (OFF_XPRE + BB*TSN*512)    // [B][T][128] a = q/sqrt(H) f32
#define OFF_HALL  (OFF_AQ + BB*TSN*128)      // [B][T][128] h_t f32
#define OFF_APRE  (OFF_HALL + BB*TSN*128)    // [B][T][128] uint4: 4x pk2(A1_g, A2_g) f16, A_p = W_hg @ a^p
// total floats = OFF_APRE + BB*TSN*128*2 = 5,415,424 (~20.7 MB)

typedef _Float16 hf2 __attribute__((ext_vector_type(2)));

__device__ __forceinline__ float rcp_f(float x) { return __builtin_amdgcn_rcpf(x); }
__device__ __forceinline__ float sigm_f(float x) { return rcp_f(1.0f + __expf(-x)); }
__device__ __forceinline__ float tanh_f(float x) { return fmaf(2.0f, rcp_f(1.0f + __expf(-2.0f * x)), -1.0f); }
__device__ __forceinline__ float sigm_p(float x) { return 1.0f / (1.0f + __expf(-x)); }

#if __has_builtin(__builtin_amdgcn_fdot2)
__device__ __forceinline__ float dot2f(hf2 a, hf2 b, float c) {
  return __builtin_amdgcn_fdot2(a, b, c, false);
}
#else
__device__ __forceinline__ float dot2f(hf2 a, hf2 b, float c) {
  return fmaf((float)a.x, (float)b.x, fmaf((float)a.y, (float)b.y, c));
}
#endif

__device__ __forceinline__ hf2 mk2(float a, float b) {
  hf2 v; v.x = (_Float16)a; v.y = (_Float16)b; return v;
}
__device__ __forceinline__ unsigned pk2(float a, float b) {
  return __builtin_bit_cast(unsigned, __builtin_amdgcn_cvt_pkrtz(a, b));
}
__device__ __forceinline__ hf2 u2h(unsigned u) { return __builtin_bit_cast(hf2, u); }

// ---- wave-64 sum: DPP (VALU-pipe, ~5cyc/level) with shfl fallback. Result valid in lane 63. ----
#if __has_builtin(__builtin_amdgcn_update_dpp)
template <int CTRL>
__device__ __forceinline__ float dppadd(float x) {
  int v = __builtin_amdgcn_update_dpp(0, __builtin_bit_cast(int, x), CTRL, 0xf, 0xf, true);
  return x + __builtin_bit_cast(float, v);
}
__device__ __forceinline__ float wsum64(float x) {
  x = dppadd<0x111>(x);   // row_shr:1
  x = dppadd<0x112>(x);   // row_shr:2
  x = dppadd<0x114>(x);   // row_shr:4
  x = dppadd<0x118>(x);   // row_shr:8  -> lane15 of each 16-row has row sum
  x = dppadd<0x142>(x);   // row_bcast:15 -> lane31/63 have 32-lane sums
  x = dppadd<0x143>(x);   // row_bcast:31 -> lane63 has 64-lane sum
  return x;
}
#else
__device__ __forceinline__ float wsum64(float x) {
  x += __shfl_xor(x, 1);  x += __shfl_xor(x, 2);  x += __shfl_xor(x, 4);
  x += __shfl_xor(x, 8);  x += __shfl_xor(x, 16); x += __shfl_xor(x, 32);
  return x;
}
#endif

// ---- lgkm-only workgroup barrier: does NOT drain vmcnt, so in-flight global
// prefetch loads survive across it (HIP __syncthreads emits a full
// vmcnt(0)+lgkmcnt(0) drain, which serializes every scan step on the L3/HBM
// round trip of the just-issued prefetches). Only LDS (ch[], part[]) needs
// cross-wave visibility here -> lgkmcnt(0) suffices. sched_barrier(0) on both
// sides pins LDS ops to their side of the barrier (guide rule #18).
__device__ __forceinline__ void ldsbar() {
  __builtin_amdgcn_sched_barrier(0);
  asm volatile("s_waitcnt lgkmcnt(0)" ::: "memory");
  __builtin_amdgcn_s_barrier();
  __builtin_amdgcn_sched_barrier(0);
}

// ---------------- P0: transpose weights + rowsums ----------------
__global__ void k_prep(const float* __restrict__ W_in, const float* __restrict__ W_ii,
                       const float* __restrict__ W_if, const float* __restrict__ W_ig,
                       const float* __restrict__ W_io, const float* __restrict__ W_xo,
                       const float* __restrict__ W_q,  const float* __restrict__ W_hi,
                       const float* __restrict__ W_hf, const float* __restrict__ W_hg,
                       const float* __restrict__ W_ho, float* __restrict__ ws) {
  int m = blockIdx.x;  // 0..11
  if (m == 11) {
    for (int idx = threadIdx.x; idx < 512; idx += blockDim.x) {
      int g = idx >> 7, r = idx & 127;
      const float* W = (g == 0) ? W_hi : (g == 1) ? W_hf : (g == 2) ? W_hg : W_ho;
      float s = 0.f;
      for (int c = 0; c < 128; ++c) s += W[r * 128 + c];
      ws[OFF_RS + r * 4 + g] = s;
    }
    return;
  }
  const float* src;
  float* dst;
  int C;
  if (m == 0) { src = W_in; dst = ws + OFF_WINT; C = 64; }
  else {
    const float* s[10] = {W_ii, W_if, W_ig, W_io, W_xo, W_q, W_hi, W_hf, W_hg, W_ho};
    src = s[m - 1];
    dst = ws + OFF_WT + (size_t)(m - 1) * 16384;
    C = 128;
  }
  int n = 128 * C;
  for (int idx = threadIdx.x; idx < n; idx += blockDim.x) {
    int r = idx / C, c = idx - r * C;
    dst[c * 128 + r] = src[idx];   // dst[c][r] = W[r][c]
  }
}

// ---------------- P1: x-side projections + A-moment precompute, 8 t's per block ----------------
__global__ __launch_bounds__(128)
void k_xproj(const float* __restrict__ x,
             const float* __restrict__ b_in,
             const float* __restrict__ b_ii, const float* __restrict__ b_hi,
             const float* __restrict__ b_if, const float* __restrict__ b_hf,
             const float* __restrict__ b_ig, const float* __restrict__ b_hg,
             const float* __restrict__ b_io, const float* __restrict__ b_ho,
             const float* __restrict__ b_xo, const float* __restrict__ b_q,
             float* __restrict__ ws) {
  const int tid = threadIdx.x;
  const int b  = blockIdx.x >> 6;
  const int t0 = (blockIdx.x & 63) * 8;

  __shared__ __align__(16) float xsT[MELN * 8];   // [m][tt]
  __shared__ __align__(16) float xpsT[128 * 8];   // [c][tt]   (xp, then a)
  __shared__ __align__(16) float xosT[128 * 8];   // [c][tt]   (x_o, then a^2)

  const float* WinT = ws + OFF_WINT;
  const float* WT   = ws + OFF_WT;
  float* Xpre = ws + OFF_XPRE;
  float* aq   = ws + OFF_AQ;

  #pragma unroll
  for (int k = 0; k < 4; ++k) {
    int mm = k * 16 + (tid >> 3);
    int tt = tid & 7;
    xsT[mm * 8 + tt] = x[((size_t)b * MELN + mm) * TSN + t0 + tt];
  }
  __syncthreads();

  // xp rows: thread = output feature
  float acc8[8];
  {
    float bi = b_in[tid];
    #pragma unroll
    for (int j = 0; j < 8; ++j) acc8[j] = bi;
  }
  for (int mI = 0; mI < MELN; ++mI) {
    float w = WinT[mI * 128 + tid];
    float4 xa = *(const float4*)&xsT[mI * 8];
    float4 xb = *(const float4*)&xsT[mI * 8 + 4];
    acc8[0] = fmaf(w, xa.x, acc8[0]); acc8[1] = fmaf(w, xa.y, acc8[1]);
    acc8[2] = fmaf(w, xa.z, acc8[2]); acc8[3] = fmaf(w, xa.w, acc8[3]);
    acc8[4] = fmaf(w, xb.x, acc8[4]); acc8[5] = fmaf(w, xb.y, acc8[5]);
    acc8[6] = fmaf(w, xb.z, acc8[6]); acc8[7] = fmaf(w, xb.w, acc8[7]);
  }
  *(float4*)&xpsT[tid * 8]     = make_float4(acc8[0], acc8[1], acc8[2], acc8[3]);
  *(float4*)&xpsT[tid * 8 + 4] = make_float4(acc8[4], acc8[5], acc8[6], acc8[7]);
  __syncthreads();

  // gate x-terms (ii,if,ig,io) + xo
  float accg[5][8];
  {
    float bsum[5];
    bsum[0] = b_ii[tid] + b_hi[tid];
    bsum[1] = b_if[tid] + b_hf[tid];
    bsum[2] = b_ig[tid] + b_hg[tid];
    bsum[3] = b_io[tid] + b_ho[tid];
    bsum[4] = b_xo[tid];
    #pragma unroll
    for (int g = 0; g < 5; ++g)
      #pragma unroll
      for (int j = 0; j < 8; ++j) accg[g][j] = bsum[g];
  }
  #pragma unroll 2
  for (int c = 0; c < 128; ++c) {
    const float4 xa = *(const float4*)&xpsT[c * 8];
    const float4 xb = *(const float4*)&xpsT[c * 8 + 4];
    #pragma unroll
    for (int g = 0; g < 5; ++g) {
      const float w = WT[g * 16384 + c * 128 + tid];
      accg[g][0] = fmaf(w, xa.x, accg[g][0]);
      accg[g][1] = fmaf(w, xa.y, accg[g][1]);
      accg[g][2] = fmaf(w, xa.z, accg[g][2]);
      accg[g][3] = fmaf(w, xa.w, accg[g][3]);
      accg[g][4] = fmaf(w, xb.x, accg[g][4]);
      accg[g][5] = fmaf(w, xb.y, accg[g][5]);
      accg[g][6] = fmaf(w, xb.z, accg[g][6]);
      accg[g][7] = fmaf(w, xb.w, accg[g][7]);
    }
  }
  {
    size_t base = ((size_t)b * TSN + t0) * 512;
    #pragma unroll
    for (int tt = 0; tt < 8; ++tt)
      *(float4*)&Xpre[base + (size_t)tt * 512 + tid * 4] =
          make_float4(accg[0][tt], accg[1][tt], accg[2][tt], accg[3][tt]);
  }
  {
    #pragma unroll
    for (int tt = 0; tt < 8; ++tt) xosT[tid * 8 + tt] = sigm_p(accg[4][tt]);
  }
  __syncthreads();

  // q projection on x_o -> a = q / sqrt(H)
  float accq[8];
  {
    float bq = b_q[tid];
    #pragma unroll
    for (int j = 0; j < 8; ++j) accq[j] = bq;
  }
  #pragma unroll 2
  for (int c = 0; c < 128; ++c) {
    const float w = WT[5 * 16384 + c * 128 + tid];
    const float4 xa = *(const float4*)&xosT[c * 8];
    const float4 xb = *(const float4*)&xosT[c * 8 + 4];
    accq[0] = fmaf(w, xa.x, accq[0]); accq[1] = fmaf(w, xa.y, accq[1]);
    accq[2] = fmaf(w, xa.z, accq[2]); accq[3] = fmaf(w, xa.w, accq[3]);
    accq[4] = fmaf(w, xb.x, accq[4]); accq[5] = fmaf(w, xb.y, accq[5]);
    accq[6] = fmaf(w, xb.z, accq[6]); accq[7] = fmaf(w, xb.w, accq[7]);
  }
  float av[8];
  #pragma unroll
  for (int tt = 0; tt < 8; ++tt) {
    av[tt] = accq[tt] * 0.08838834764831845f;
    aq[((size_t)b * TSN + t0 + tt) * 128 + tid] = av[tt];
  }

  // ---- A-moment precompute (MERGED): A1 = W_hg @ a, A2 = W_hg @ a^2 (4 gates),
  // one pass over the weights (each W element loaded once, feeds both moments). ----
  __syncthreads();   // q-loop reads of xosT complete
  *(float4*)&xpsT[tid * 8]     = make_float4(av[0], av[1], av[2], av[3]);
  *(float4*)&xpsT[tid * 8 + 4] = make_float4(av[4], av[5], av[6], av[7]);
  *(float4*)&xosT[tid * 8]     = make_float4(av[0]*av[0], av[1]*av[1], av[2]*av[2], av[3]*av[3]);
  *(float4*)&xosT[tid * 8 + 4] = make_float4(av[4]*av[4], av[5]*av[5], av[6]*av[6], av[7]*av[7]);
  __syncthreads();
  float accA[4][8], accB[4][8];
  #pragma unroll
  for (int g = 0; g < 4; ++g)
    #pragma unroll
    for (int j = 0; j < 8; ++j) { accA[g][j] = 0.f; accB[g][j] = 0.f; }
  #pragma unroll 2
  for (int c = 0; c < 128; ++c) {
    const float4 xa = *(const float4*)&xpsT[c * 8];
    const float4 xb = *(const float4*)&xpsT[c * 8 + 4];
    const float4 ya = *(const float4*)&xosT[c * 8];
    const float4 yb = *(const float4*)&xosT[c * 8 + 4];
    #pragma unroll
    for (int g = 0; g < 4; ++g) {
      const float w = WT[(6 + g) * 16384 + c * 128 + tid];
      accA[g][0] = fmaf(w, xa.x, accA[g][0]);
      accA[g][1] = fmaf(w, xa.y, accA[g][1]);
      accA[g][2] = fmaf(w, xa.z, accA[g][2]);
      accA[g][3] = fmaf(w, xa.w, accA[g][3]);
      accA[g][4] = fmaf(w, xb.x, accA[g][4]);
      accA[g][5] = fmaf(w, xb.y, accA[g][5]);
      accA[g][6] = fmaf(w, xb.z, accA[g][6]);
      accA[g][7] = fmaf(w, xb.w, accA[g][7]);
      accB[g][0] = fmaf(w, ya.x, accB[g][0]);
      accB[g][1] = fmaf(w, ya.y, accB[g][1]);
      accB[g][2] = fmaf(w, ya.z, accB[g][2]);
      accB[g][3] = fmaf(w, ya.w, accB[g][3]);
      accB[g][4] = fmaf(w, yb.x, accB[g][4]);
      accB[g][5] = fmaf(w, yb.y, accB[g][5]);
      accB[g][6] = fmaf(w, yb.z, accB[g][6]);
      accB[g][7] = fmaf(w, yb.w, accB[g][7]);
    }
  }
  {
    uint4* APre4 = (uint4*)(ws + OFF_APRE);
    #pragma unroll
    for (int tt = 0; tt < 8; ++tt) {
      uint4 u;
      u.x = pk2(accA[0][tt], accB[0][tt]);
      u.y = pk2(accA[1][tt], accB[1][tt]);
      u.z = pk2(accA[2][tt], accB[2][tt]);
      u.w = pk2(accA[3][tt], accB[3][tt]);
      APre4[((size_t)b * TSN + t0 + tt) * 128 + tid] = u;
    }
  }
}

// ---------------- P2: scan. 128 thr (2 waves); DPP reduce + distance-2 register prefetch.
// Barriers are lgkm-only (ldsbar) so prefetch global loads stay in flight across them. ----
__global__ __launch_bounds__(128, 1)
void k_scan(const float* __restrict__ W_k,  const float* __restrict__ b_k,
            const float* __restrict__ W_v,  const float* __restrict__ b_v,
            const float* __restrict__ W_ao, const float* __restrict__ b_ao,
            float* __restrict__ ws) {
  const int tid  = threadIdx.x;    // row 0..127
  const int lane = tid & 63;
  const int wid  = tid >> 6;       // wave 0..1
  const int b    = blockIdx.x;

  __shared__ __align__(16) _Float16 ch[128];     // c as f16 (direct b16 stores)
  __shared__ __align__(16) float part[16];       // [wave][moment 0..4] (stride 8)

  // full W_k row in registers as 64 f16 pairs (64 VGPRs)
  hf2 wkk2[64];
  #pragma unroll
  for (int p = 0; p < 64; ++p)
    wkk2[p] = mk2(W_k[(size_t)tid * 128 + 2 * p], W_k[(size_t)tid * 128 + 2 * p + 1]);
  const float bkr = b_k[tid];
  const float4 RSv = *(const float4*)&ws[OFF_RS + tid * 4];   // rowsums (ii,if,ig,io)

  // collapsed attention-output constants: h = s1*(attn.o) + s2
  float s1 = 0.f, s2 = 0.f;
  for (int j = 0; j < 128; ++j) {
    s1 = fmaf(W_ao[j], W_v[j], s1);
    s2 = fmaf(W_ao[j], b_v[j], s2);
  }
  s2 += b_ao[0];
  const float inv128 = 0.0078125f;
  const float s1i = s1 * inv128;

  const float* Xb = ws + OFF_XPRE + (size_t)b * TSN * 512;
  const float* ab = ws + OFF_AQ   + (size_t)b * TSN * 128;
  float*       Hb = ws + OFF_HALL + (size_t)b * TSN * 128;
  const uint4* APb = (const uint4*)(ws + OFF_APRE) + (size_t)b * TSN * 128;

  const uint4* c4u = (const uint4*)ch;

  // even/odd register sets (distance-2 prefetch; static names per rule #20)
  float4 X4e = *(const float4*)&Xb[tid * 4];                    // t=0
  float4 X4o = *(const float4*)&Xb[512 + tid * 4];              // t=1
  float  are = ab[tid];                                         // t=0
  float  aro = ab[128 + tid];                                   // t=1
  uint4  Ae  = APb[tid];   // dummy finite (t=0 has gamma=0)
  uint4  Ao  = APb[tid];   // A slot 0, used at t=1

  float c_reg = 0.f;
  float g0 = 0.f;                  // gamma0
  hf2   g12 = u2h(0u);             // (gamma1, gamma2) packed f16

// One scan step. X4v/Argv are reloaded immediately after their last use (the
// gate pre-activations) -> ~2 full steps of in-flight cover, since the
// lgkm-only barriers do not drain vmcnt. arv reloads at the end (last use
// is hn), also 2-step cover.
#define SCAN_STEP(T, X4v, arv, Argv)                                          \
  {                                                                           \
    const float pi = dot2f(u2h((Argv).x), g12, fmaf(g0, RSv.x, (X4v).x));     \
    const float pf = dot2f(u2h((Argv).y), g12, fmaf(g0, RSv.y, (X4v).y));     \
    const float pg = dot2f(u2h((Argv).z), g12, fmaf(g0, RSv.z, (X4v).z));     \
    const float po = dot2f(u2h((Argv).w), g12, fmaf(g0, RSv.w, (X4v).w));     \
    /* early prefetch into this parity's regs (X,A last used above) */        \
    {                                                                         \
      const int tx = ((T) + 2 < TSN) ? (T) + 2 : TSN - 1;                     \
      (X4v) = *(const float4*)&Xb[(size_t)tx * 512 + tid * 4];                \
      const int ta = ((T) + 1 < TSN) ? (T) + 1 : TSN - 1;                     \
      (Argv) = APb[(size_t)ta * 128 + tid];                                   \
    }                                                                         \
    const float gi = sigm_f(pi);                                              \
    const float gf = sigm_f(pf);                                              \
    const float gg = tanh_f(pg);                                              \
    const float go = sigm_f(po);                                              \
    c_reg = fmaf(gf, c_reg, gi * gg);                                         \
    ch[tid] = (_Float16)c_reg;                                                \
    ldsbar();  /* [1] c visible (lgkm-only) */                                \
    float ka0 = 0.f, ka1 = 0.f, ka2 = 0.f, ka3 = 0.f;                         \
    _Pragma("unroll")                                                         \
    for (int u = 0; u < 16; ++u) {                                            \
      const uint4 cv = c4u[u];                                                \
      ka0 = dot2f(wkk2[u * 4 + 0], u2h(cv.x), ka0);                           \
      ka1 = dot2f(wkk2[u * 4 + 1], u2h(cv.y), ka1);                           \
      ka2 = dot2f(wkk2[u * 4 + 2], u2h(cv.z), ka2);                           \
      ka3 = dot2f(wkk2[u * 4 + 3], u2h(cv.w), ka3);                           \
    }                                                                         \
    const float kr = ((ka0 + ka1) + (ka2 + ka3)) + bkr;                       \
    const float kp2 = kr * kr;                                                \
    float m0 = kr, m1 = go, m2 = kp2, m3 = go * kr, m4 = go * kp2;            \
    m0 = wsum64(m0); m1 = wsum64(m1); m2 = wsum64(m2);                        \
    m3 = wsum64(m3); m4 = wsum64(m4);                                         \
    if (lane == 63) {                                                         \
      part[wid * 8 + 0] = m0; part[wid * 8 + 1] = m1;                         \
      part[wid * 8 + 2] = m2; part[wid * 8 + 3] = m3;                         \
      part[wid * 8 + 4] = m4;                                                 \
    }                                                                         \
    ldsbar();  /* [2] partials visible (lgkm-only) */                         \
    const float4 pa = *(const float4*)&part[0];                               \
    const float4 pb = *(const float4*)&part[8];                               \
    const float D1 = pa.x + pb.x;                                             \
    const float N0 = pa.y + pb.y;                                             \
    const float D2 = pa.z + pb.z;                                             \
    const float N1 = pa.w + pb.w;                                             \
    const float N2 = part[4] + part[12];                                      \
    const float t1 = D1 * inv128;                                             \
    g0 = fmaf(s1i, N0, s2);                                                   \
    const float gm1 = s1i * (N1 - N0 * t1);                                   \
    const float gm2 = s1i * (0.5f * N2 - (N1 * D1 + 0.5f * N0 * D2) * inv128  \
                             + N0 * t1 * t1);                                 \
    const float hn = fmaf(fmaf(gm2, (arv), gm1), (arv), g0);                  \
    Hb[(size_t)(T) * 128 + tid] = hn;                                         \
    g12 = u2h(pk2(gm1, gm2));                                                 \
    /* ar prefetch (distance-2, after last use) */                            \
    {                                                                         \
      const int tr = ((T) + 2 < TSN) ? (T) + 2 : TSN - 1;                     \
      (arv) = ab[(size_t)tr * 128 + tid];                                     \
    }                                                                         \
  }

  for (int k = 0; k < TSN / 2; ++k) {
    SCAN_STEP(2 * k,     X4e, are, Ae);
    SCAN_STEP(2 * k + 1, X4o, aro, Ao);
  }
#undef SCAN_STEP
}

// ---------------- P3: y = Hall @ W_out^T + b_out -> fp32 (B,C,T) ----------------
__global__ __launch_bounds__(256)
void k_out(const float* __restrict__ W_out, const float* __restrict__ b_out,
           const float* __restrict__ ws, float* __restrict__ out) {
  const int tid = threadIdx.x;
  const int b  = blockIdx.x >> 3;
  const int t0 = (blockIdx.x & 7) * 64;

  // stride 129 (odd): 129 mod 32 = 1 -> the read Hs[tt*129+i] (lanes vary tt)
  // walks all 32 banks. Previous stride 136 (mod 32 = 8) was a 16-way conflict.
  __shared__ float Hs[64 * 129];

  const float* Hb = ws + OFF_HALL + ((size_t)b * TSN + t0) * 128;
  for (int k = 0; k < 32; ++k) {
    const int idx = k * 256 + tid;
    Hs[(idx >> 7) * 129 + (idx & 127)] = Hb[idx];
  }
  __syncthreads();

  const int tt = tid & 63;
  const int c0 = (tid >> 6) * 5;
  for (int j = 0; j < 5; ++j) {
    const int c = c0 + j;
    float s = b_out[c];
    for (int i = 0; i < 128; ++i)
      s = fmaf(Hs[tt * 129 + i], W_out[c * 128 + i], s);
    out[((size_t)b * CCN + c) * TSN + t0 + tt] = s;
  }
}

extern "C" void kernel_launch(void* const* d_in, const int* in_sizes, int n_in,
                              void* d_out, int out_size, void* d_ws, size_t ws_size,
                              hipStream_t stream) {
  const float* x    = (const float*)d_in[0];
  const float* W_in = (const float*)d_in[1];
  const float* b_in = (const float*)d_in[2];
  const float* W_out= (const float*)d_in[3];
  const float* b_out= (const float*)d_in[4];
  const float* W_ii = (const float*)d_in[5];
  const float* b_ii = (const float*)d_in[6];
  const float* W_hi = (const float*)d_in[7];
  const float* b_hi = (const float*)d_in[8];
  const float* W_if = (const float*)d_in[9];
  const float* b_if = (const float*)d_in[10];
  const float* W_hf = (const float*)d_in[11];
  const float* b_hf = (const float*)d_in[12];
  const float* W_ig = (const float*)d_in[13];
  const float* b_ig = (const float*)d_in[14];
  const float* W_hg = (const float*)d_in[15];
  const float* b_hg = (const float*)d_in[16];
  const float* W_io = (const float*)d_in[17];
  const float* b_io = (const float*)d_in[18];
  const float* W_ho = (const float*)d_in[19];
  const float* b_ho = (const float*)d_in[20];
  const float* W_xo = (const float*)d_in[21];
  const float* b_xo = (const float*)d_in[22];
  const float* W_q  = (const float*)d_in[23];
  const float* b_q  = (const float*)d_in[24];
  const float* W_k  = (const float*)d_in[25];
  const float* b_k  = (const float*)d_in[26];
  const float* W_v  = (const float*)d_in[27];
  const float* b_v  = (const float*)d_in[28];
  const float* W_ao = (const float*)d_in[29];
  const float* b_ao = (const float*)d_in[30];

  float* ws = (float*)d_ws;
  float* out = (float*)d_out;

  k_prep<<<12, 256, 0, stream>>>(W_in, W_ii, W_if, W_ig, W_io, W_xo, W_q,
                                 W_hi, W_hf, W_hg, W_ho, ws);
  k_xproj<<<512, 128, 0, stream>>>(x, b_in, b_ii, b_hi, b_if, b_hf, b_ig, b_hg,
                                   b_io, b_ho, b_xo, b_q, ws);
  k_scan<<<BB, 128, 0, stream>>>(W_k, b_k, W_v, b_v, W_ao, b_ao, ws);
  k_out<<<BB * 8, 256, 0, stream>>>(W_out, b_out, ws, out);
}

// Round 6
// 459.631 us; speedup vs baseline: 1.5743x; 1.0408x over previous
//
#include <hip/hip_runtime.h>
#include <hip/hip_bf16.h>

// Problem constants
#define BB 8
#define MELN 64
#define TSN 512
#define HHN 128
#define CCN 20

// ws layout (float offsets)
#define OFF_WINT  0                          // W_in^T [64][128]
#define OFF_WT    8192                       // 5x [128][128] transposed f32: ii,if,ig,io,xo
#define OFF_WQ16  (OFF_WT + 5*16384)         // [64][128] u32: pk2(WqT[2p][r], WqT[2p+1][r])
#define OFF_WH16  (OFF_WT + 6*16384)         // [4][64][128] u32: same packing for hi,hf,hg,ho
#define OFF_RS    (OFF_WT + 10*16384)        // [128][4] rowsums of W_hi,W_hf,W_hg,W_ho
#define OFF_XPRE  (OFF_RS + 512)             // [B][T][128 rows][4 gates] x-terms (+both biases) f32
#define OFF_AQ    (OFF_XPRE + BB*TSN*512)    // [B][T][128] a = q/sqrt(H) f32
#define OFF_HALL  (OFF_AQ + BB*TSN*128)      // [B][T][128] h_t f32
#define OFF_APRE  (OFF_HALL + BB*TSN*128)    // [B][T][128] uint4: 4x pk2(A1_g, A2_g) f16
// total floats = OFF_APRE + BB*TSN*128*2 = 5,415,424 (~20.7 MB)

typedef _Float16 hf2 __attribute__((ext_vector_type(2)));

__device__ __forceinline__ float rcp_f(float x) { return __builtin_amdgcn_rcpf(x); }
__device__ __forceinline__ float sigm_f(float x) { return rcp_f(1.0f + __expf(-x)); }
__device__ __forceinline__ float tanh_f(float x) { return fmaf(2.0f, rcp_f(1.0f + __expf(-2.0f * x)), -1.0f); }
__device__ __forceinline__ float sigm_p(float x) { return 1.0f / (1.0f + __expf(-x)); }

#if __has_builtin(__builtin_amdgcn_fdot2)
__device__ __forceinline__ float dot2f(hf2 a, hf2 b, float c) {
  return __builtin_amdgcn_fdot2(a, b, c, false);
}
#else
__device__ __forceinline__ float dot2f(hf2 a, hf2 b, float c) {
  return fmaf((float)a.x, (float)b.x, fmaf((float)a.y, (float)b.y, c));
}
#endif

__device__ __forceinline__ hf2 mk2(float a, float b) {
  hf2 v; v.x = (_Float16)a; v.y = (_Float16)b; return v;
}
__device__ __forceinline__ unsigned pk2(float a, float b) {
  return __builtin_bit_cast(unsigned, __builtin_amdgcn_cvt_pkrtz(a, b));
}
__device__ __forceinline__ unsigned mku(float a, float b) {
  return __builtin_bit_cast(unsigned, mk2(a, b));   // RTE pack (2x cvt)
}
__device__ __forceinline__ hf2 u2h(unsigned u) { return __builtin_bit_cast(hf2, u); }

// ---- wave-64 sum: DPP (VALU-pipe) with shfl fallback. Result valid in lane 63. ----
#if __has_builtin(__builtin_amdgcn_update_dpp)
template <int CTRL>
__device__ __forceinline__ float dppadd(float x) {
  int v = __builtin_amdgcn_update_dpp(0, __builtin_bit_cast(int, x), CTRL, 0xf, 0xf, true);
  return x + __builtin_bit_cast(float, v);
}
__device__ __forceinline__ float wsum64(float x) {
  x = dppadd<0x111>(x);   // row_shr:1
  x = dppadd<0x112>(x);   // row_shr:2
  x = dppadd<0x114>(x);   // row_shr:4
  x = dppadd<0x118>(x);   // row_shr:8  -> lane15 of each 16-row has row sum
  x = dppadd<0x142>(x);   // row_bcast:15 -> lane31/63 have 32-lane sums
  x = dppadd<0x143>(x);   // row_bcast:31 -> lane63 has 64-lane sum
  return x;
}
#else
__device__ __forceinline__ float wsum64(float x) {
  x += __shfl_xor(x, 1);  x += __shfl_xor(x, 2);  x += __shfl_xor(x, 4);
  x += __shfl_xor(x, 8);  x += __shfl_xor(x, 16); x += __shfl_xor(x, 32);
  return x;
}
#endif

// ---- lgkm-only workgroup barrier: does NOT drain vmcnt, so in-flight global
// prefetch loads survive across it. sched_barrier(0) pins LDS ops (rule #18).
__device__ __forceinline__ void ldsbar() {
  __builtin_amdgcn_sched_barrier(0);
  asm volatile("s_waitcnt lgkmcnt(0)" ::: "memory");
  __builtin_amdgcn_s_barrier();
  __builtin_amdgcn_sched_barrier(0);
}

// ---------------- P0: weight prep ----------------
// m==0: W_in transpose. m 1..5: transpose ii,if,ig,io,xo (f32).
// m==6: W_q -> f16-pair pack. m 7..10: W_hi..W_ho -> f16-pair pack. m==11: rowsums.
__global__ void k_prep(const float* __restrict__ W_in, const float* __restrict__ W_ii,
                       const float* __restrict__ W_if, const float* __restrict__ W_ig,
                       const float* __restrict__ W_io, const float* __restrict__ W_xo,
                       const float* __restrict__ W_q,  const float* __restrict__ W_hi,
                       const float* __restrict__ W_hf, const float* __restrict__ W_hg,
                       const float* __restrict__ W_ho, float* __restrict__ ws) {
  int m = blockIdx.x;  // 0..11
  if (m == 11) {
    for (int idx = threadIdx.x; idx < 512; idx += blockDim.x) {
      int g = idx >> 7, r = idx & 127;
      const float* W = (g == 0) ? W_hi : (g == 1) ? W_hf : (g == 2) ? W_hg : W_ho;
      float s = 0.f;
      for (int c = 0; c < 128; ++c) s += W[r * 128 + c];
      ws[OFF_RS + r * 4 + g] = s;
    }
    return;
  }
  if (m == 0) {
    for (int idx = threadIdx.x; idx < 128 * 64; idx += blockDim.x) {
      int r = idx >> 6, c = idx & 63;
      ws[OFF_WINT + c * 128 + r] = W_in[idx];
    }
    return;
  }
  const float* s[10] = {W_ii, W_if, W_ig, W_io, W_xo, W_q, W_hi, W_hf, W_hg, W_ho};
  const float* src = s[m - 1];
  if (m <= 5) {   // f32 transpose: dst[c][r] = W[r][c]
    float* dst = ws + OFF_WT + (size_t)(m - 1) * 16384;
    for (int idx = threadIdx.x; idx < 16384; idx += blockDim.x) {
      int r = idx >> 7, c = idx & 127;
      dst[c * 128 + r] = src[idx];
    }
  } else {        // f16-pair pack along the contraction axis: dst[p][r] = (W[r][2p], W[r][2p+1])
    unsigned* dst = (m == 6)
        ? (unsigned*)(ws + OFF_WQ16)
        : (unsigned*)(ws + OFF_WH16) + (size_t)(m - 7) * 8192;
    for (int idx = threadIdx.x; idx < 8192; idx += blockDim.x) {
      int p = idx >> 7, r = idx & 127;
      dst[p * 128 + r] = mku(src[r * 128 + 2 * p], src[r * 128 + 2 * p + 1]);
    }
  }
}

// ---------------- P1: x-side projections + A-moment precompute, 8 t's per block.
// Gate x-terms in full f32; q-projection and A-moment matvecs in f16-pair dot2
// (same numeric class as k_scan's W_k@c f16 matvec, which passes at 6e-5). ----
__global__ __launch_bounds__(128)
void k_xproj(const float* __restrict__ x,
             const float* __restrict__ b_in,
             const float* __restrict__ b_ii, const float* __restrict__ b_hi,
             const float* __restrict__ b_if, const float* __restrict__ b_hf,
             const float* __restrict__ b_ig, const float* __restrict__ b_hg,
             const float* __restrict__ b_io, const float* __restrict__ b_ho,
             const float* __restrict__ b_xo, const float* __restrict__ b_q,
             float* __restrict__ ws) {
  const int tid = threadIdx.x;
  const int b  = blockIdx.x >> 6;
  const int t0 = (blockIdx.x & 63) * 8;

  __shared__ __align__(16) float xsT[MELN * 8];     // [m][tt]
  __shared__ __align__(16) float xpsT[128 * 8];     // [c][tt]  (xp, then a)
  __shared__ __align__(16) float xosT[128 * 8];     // [c][tt]  (x_o)
  __shared__ __align__(16) unsigned xo16[64 * 8];   // [p][tt] f16 pairs of sigma(xo)
  __shared__ __align__(16) unsigned ap16[64 * 8];   // [p][tt] f16 pairs of a
  __shared__ __align__(16) unsigned as16[64 * 8];   // [p][tt] f16 pairs of a^2

  const float* WinT = ws + OFF_WINT;
  const float* WT   = ws + OFF_WT;
  float* Xpre = ws + OFF_XPRE;
  float* aq   = ws + OFF_AQ;

  #pragma unroll
  for (int k = 0; k < 4; ++k) {
    int mm = k * 16 + (tid >> 3);
    int tt = tid & 7;
    xsT[mm * 8 + tt] = x[((size_t)b * MELN + mm) * TSN + t0 + tt];
  }
  __syncthreads();

  // xp rows: thread = output feature
  float acc8[8];
  {
    float bi = b_in[tid];
    #pragma unroll
    for (int j = 0; j < 8; ++j) acc8[j] = bi;
  }
  for (int mI = 0; mI < MELN; ++mI) {
    float w = WinT[mI * 128 + tid];
    float4 xa = *(const float4*)&xsT[mI * 8];
    float4 xb = *(const float4*)&xsT[mI * 8 + 4];
    acc8[0] = fmaf(w, xa.x, acc8[0]); acc8[1] = fmaf(w, xa.y, acc8[1]);
    acc8[2] = fmaf(w, xa.z, acc8[2]); acc8[3] = fmaf(w, xa.w, acc8[3]);
    acc8[4] = fmaf(w, xb.x, acc8[4]); acc8[5] = fmaf(w, xb.y, acc8[5]);
    acc8[6] = fmaf(w, xb.z, acc8[6]); acc8[7] = fmaf(w, xb.w, acc8[7]);
  }
  *(float4*)&xpsT[tid * 8]     = make_float4(acc8[0], acc8[1], acc8[2], acc8[3]);
  *(float4*)&xpsT[tid * 8 + 4] = make_float4(acc8[4], acc8[5], acc8[6], acc8[7]);
  __syncthreads();

  // gate x-terms (ii,if,ig,io) + xo — full f32
  float accg[5][8];
  {
    float bsum[5];
    bsum[0] = b_ii[tid] + b_hi[tid];
    bsum[1] = b_if[tid] + b_hf[tid];
    bsum[2] = b_ig[tid] + b_hg[tid];
    bsum[3] = b_io[tid] + b_ho[tid];
    bsum[4] = b_xo[tid];
    #pragma unroll
    for (int g = 0; g < 5; ++g)
      #pragma unroll
      for (int j = 0; j < 8; ++j) accg[g][j] = bsum[g];
  }
  #pragma unroll 2
  for (int c = 0; c < 128; ++c) {
    const float4 xa = *(const float4*)&xpsT[c * 8];
    const float4 xb = *(const float4*)&xpsT[c * 8 + 4];
    #pragma unroll
    for (int g = 0; g < 5; ++g) {
      const float w = WT[g * 16384 + c * 128 + tid];
      accg[g][0] = fmaf(w, xa.x, accg[g][0]);
      accg[g][1] = fmaf(w, xa.y, accg[g][1]);
      accg[g][2] = fmaf(w, xa.z, accg[g][2]);
      accg[g][3] = fmaf(w, xa.w, accg[g][3]);
      accg[g][4] = fmaf(w, xb.x, accg[g][4]);
      accg[g][5] = fmaf(w, xb.y, accg[g][5]);
      accg[g][6] = fmaf(w, xb.z, accg[g][6]);
      accg[g][7] = fmaf(w, xb.w, accg[g][7]);
    }
  }
  {
    size_t base = ((size_t)b * TSN + t0) * 512;
    #pragma unroll
    for (int tt = 0; tt < 8; ++tt)
      *(float4*)&Xpre[base + (size_t)tt * 512 + tid * 4] =
          make_float4(accg[0][tt], accg[1][tt], accg[2][tt], accg[3][tt]);
  }
  {
    #pragma unroll
    for (int tt = 0; tt < 8; ++tt) xosT[tid * 8 + tt] = sigm_p(accg[4][tt]);
  }
  __syncthreads();

  // pack sigma(xo) into f16 pairs along c
  {
    const int p = tid & 63;
    const int th = (tid >> 6) * 4;
    #pragma unroll
    for (int j = 0; j < 4; ++j) {
      const int tt = th + j;
      xo16[p * 8 + tt] = mku(xosT[(2 * p) * 8 + tt], xosT[(2 * p + 1) * 8 + tt]);
    }
  }
  __syncthreads();

  // q projection on x_o (f16 dot2) -> a = q / sqrt(H)
  float accq[8];
  {
    float bq = b_q[tid];
    #pragma unroll
    for (int j = 0; j < 8; ++j) accq[j] = bq;
  }
  const unsigned* WQ = (const unsigned*)(ws + OFF_WQ16);
  #pragma unroll 2
  for (int p = 0; p < 64; ++p) {
    const hf2 wq = u2h(WQ[p * 128 + tid]);
    const uint4 xa = *(const uint4*)&xo16[p * 8];
    const uint4 xb = *(const uint4*)&xo16[p * 8 + 4];
    accq[0] = dot2f(wq, u2h(xa.x), accq[0]);
    accq[1] = dot2f(wq, u2h(xa.y), accq[1]);
    accq[2] = dot2f(wq, u2h(xa.z), accq[2]);
    accq[3] = dot2f(wq, u2h(xa.w), accq[3]);
    accq[4] = dot2f(wq, u2h(xb.x), accq[4]);
    accq[5] = dot2f(wq, u2h(xb.y), accq[5]);
    accq[6] = dot2f(wq, u2h(xb.z), accq[6]);
    accq[7] = dot2f(wq, u2h(xb.w), accq[7]);
  }
  float av[8];
  #pragma unroll
  for (int tt = 0; tt < 8; ++tt) {
    av[tt] = accq[tt] * 0.08838834764831845f;
    aq[((size_t)b * TSN + t0 + tt) * 128 + tid] = av[tt];
  }

  // ---- A-moments (f16 dot2): A1 = W@a, A2 = W@a^2 for 4 gate matrices ----
  __syncthreads();   // gate/q phases' LDS reads complete
  *(float4*)&xpsT[tid * 8]     = make_float4(av[0], av[1], av[2], av[3]);
  *(float4*)&xpsT[tid * 8 + 4] = make_float4(av[4], av[5], av[6], av[7]);
  __syncthreads();
  {
    const int p = tid & 63;
    const int th = (tid >> 6) * 4;
    #pragma unroll
    for (int j = 0; j < 4; ++j) {
      const int tt = th + j;
      const float a0 = xpsT[(2 * p) * 8 + tt];
      const float a1 = xpsT[(2 * p + 1) * 8 + tt];
      ap16[p * 8 + tt] = mku(a0, a1);
      as16[p * 8 + tt] = mku(a0 * a0, a1 * a1);
    }
  }
  __syncthreads();
  float accA[4][8], accB[4][8];
  #pragma unroll
  for (int g = 0; g < 4; ++g)
    #pragma unroll
    for (int j = 0; j < 8; ++j) { accA[g][j] = 0.f; accB[g][j] = 0.f; }
  const unsigned* WH = (const unsigned*)(ws + OFF_WH16);
  #pragma unroll 2
  for (int p = 0; p < 64; ++p) {
    const uint4 aa = *(const uint4*)&ap16[p * 8];
    const uint4 ab_ = *(const uint4*)&ap16[p * 8 + 4];
    const uint4 sa = *(const uint4*)&as16[p * 8];
    const uint4 sb = *(const uint4*)&as16[p * 8 + 4];
    #pragma unroll
    for (int g = 0; g < 4; ++g) {
      const hf2 w = u2h(WH[g * 8192 + p * 128 + tid]);
      accA[g][0] = dot2f(w, u2h(aa.x), accA[g][0]);
      accA[g][1] = dot2f(w, u2h(aa.y), accA[g][1]);
      accA[g][2] = dot2f(w, u2h(aa.z), accA[g][2]);
      accA[g][3] = dot2f(w, u2h(aa.w), accA[g][3]);
      accA[g][4] = dot2f(w, u2h(ab_.x), accA[g][4]);
      accA[g][5] = dot2f(w, u2h(ab_.y), accA[g][5]);
      accA[g][6] = dot2f(w, u2h(ab_.z), accA[g][6]);
      accA[g][7] = dot2f(w, u2h(ab_.w), accA[g][7]);
      accB[g][0] = dot2f(w, u2h(sa.x), accB[g][0]);
      accB[g][1] = dot2f(w, u2h(sa.y), accB[g][1]);
      accB[g][2] = dot2f(w, u2h(sa.z), accB[g][2]);
      accB[g][3] = dot2f(w, u2h(sa.w), accB[g][3]);
      accB[g][4] = dot2f(w, u2h(sb.x), accB[g][4]);
      accB[g][5] = dot2f(w, u2h(sb.y), accB[g][5]);
      accB[g][6] = dot2f(w, u2h(sb.z), accB[g][6]);
      accB[g][7] = dot2f(w, u2h(sb.w), accB[g][7]);
    }
  }
  {
    uint4* APre4 = (uint4*)(ws + OFF_APRE);
    #pragma unroll
    for (int tt = 0; tt < 8; ++tt) {
      uint4 u;
      u.x = pk2(accA[0][tt], accB[0][tt]);
      u.y = pk2(accA[1][tt], accB[1][tt]);
      u.z = pk2(accA[2][tt], accB[2][tt]);
      u.w = pk2(accA[3][tt], accB[3][tt]);
      APre4[((size_t)b * TSN + t0 + tt) * 128 + tid] = u;
    }
  }
}

// ---------------- P2: scan. 128 thr (2 waves); DPP reduce + distance-2 register prefetch.
// Barriers are lgkm-only (ldsbar) so prefetch global loads stay in flight across them. ----
__global__ __launch_bounds__(128, 1)
void k_scan(const float* __restrict__ W_k,  const float* __restrict__ b_k,
            const float* __restrict__ W_v,  const float* __restrict__ b_v,
            const float* __restrict__ W_ao, const float* __restrict__ b_ao,
            float* __restrict__ ws) {
  const int tid  = threadIdx.x;    // row 0..127
  const int lane = tid & 63;
  const int wid  = tid >> 6;       // wave 0..1
  const int b    = blockIdx.x;

  __shared__ __align__(16) _Float16 ch[128];     // c as f16 (direct b16 stores)
  __shared__ __align__(16) float part[16];       // [wave][moment 0..4] (stride 8)

  // full W_k row in registers as 64 f16 pairs (64 VGPRs)
  hf2 wkk2[64];
  #pragma unroll
  for (int p = 0; p < 64; ++p)
    wkk2[p] = mk2(W_k[(size_t)tid * 128 + 2 * p], W_k[(size_t)tid * 128 + 2 * p + 1]);
  const float bkr = b_k[tid];
  const float4 RSv = *(const float4*)&ws[OFF_RS + tid * 4];   // rowsums (ii,if,ig,io)

  // collapsed attention-output constants: h = s1*(attn.o) + s2
  float s1 = 0.f, s2 = 0.f;
  for (int j = 0; j < 128; ++j) {
    s1 = fmaf(W_ao[j], W_v[j], s1);
    s2 = fmaf(W_ao[j], b_v[j], s2);
  }
  s2 += b_ao[0];
  const float inv128 = 0.0078125f;
  const float s1i = s1 * inv128;

  const float* Xb = ws + OFF_XPRE + (size_t)b * TSN * 512;
  const float* ab = ws + OFF_AQ   + (size_t)b * TSN * 128;
  float*       Hb = ws + OFF_HALL + (size_t)b * TSN * 128;
  const uint4* APb = (const uint4*)(ws + OFF_APRE) + (size_t)b * TSN * 128;

  const uint4* c4u = (const uint4*)ch;

  // even/odd register sets (distance-2 prefetch; static names per rule #20)
  float4 X4e = *(const float4*)&Xb[tid * 4];                    // t=0
  float4 X4o = *(const float4*)&Xb[512 + tid * 4];              // t=1
  float  are = ab[tid];                                         // t=0
  float  aro = ab[128 + tid];                                   // t=1
  uint4  Ae  = APb[tid];   // dummy finite (t=0 has gamma=0)
  uint4  Ao  = APb[tid];   // A slot 0, used at t=1

  float c_reg = 0.f;
  float g0 = 0.f;                  // gamma0
  hf2   g12 = u2h(0u);             // (gamma1, gamma2) packed f16

#define SCAN_STEP(T, X4v, arv, Argv)                                          \
  {                                                                           \
    const float pi = dot2f(u2h((Argv).x), g12, fmaf(g0, RSv.x, (X4v).x));     \
    const float pf = dot2f(u2h((Argv).y), g12, fmaf(g0, RSv.y, (X4v).y));     \
    const float pg = dot2f(u2h((Argv).z), g12, fmaf(g0, RSv.z, (X4v).z));     \
    const float po = dot2f(u2h((Argv).w), g12, fmaf(g0, RSv.w, (X4v).w));     \
    /* early prefetch into this parity's regs (X,A last used above) */        \
    {                                                                         \
      const int tx = ((T) + 2 < TSN) ? (T) + 2 : TSN - 1;                     \
      (X4v) = *(const float4*)&Xb[(size_t)tx * 512 + tid * 4];                \
      const int ta = ((T) + 1 < TSN) ? (T) + 1 : TSN - 1;                     \
      (Argv) = APb[(size_t)ta * 128 + tid];                                   \
    }                                                                         \
    const float gi = sigm_f(pi);                                              \
    const float gf = sigm_f(pf);                                              \
    const float gg = tanh_f(pg);                                              \
    const float go = sigm_f(po);                                              \
    c_reg = fmaf(gf, c_reg, gi * gg);                                         \
    ch[tid] = (_Float16)c_reg;                                                \
    ldsbar();  /* [1] c visible (lgkm-only) */                                \
    float ka0 = 0.f, ka1 = 0.f, ka2 = 0.f, ka3 = 0.f;                         \
    _Pragma("unroll")                                                         \
    for (int u = 0; u < 16; ++u) {                                            \
      const uint4 cv = c4u[u];                                                \
      ka0 = dot2f(wkk2[u * 4 + 0], u2h(cv.x), ka0);                           \
      ka1 = dot2f(wkk2[u * 4 + 1], u2h(cv.y), ka1);                           \
      ka2 = dot2f(wkk2[u * 4 + 2], u2h(cv.z), ka2);                           \
      ka3 = dot2f(wkk2[u * 4 + 3], u2h(cv.w), ka3);                           \
    }                                                                         \
    const float kr = ((ka0 + ka1) + (ka2 + ka3)) + bkr;                       \
    const float kp2 = kr * kr;                                                \
    float m0 = kr, m1 = go, m2 = kp2, m3 = go * kr, m4 = go * kp2;            \
    m0 = wsum64(m0); m1 = wsum64(m1); m2 = wsum64(m2);                        \
    m3 = wsum64(m3); m4 = wsum64(m4);                                         \
    if (lane == 63) {                                                         \
      part[wid * 8 + 0] = m0; part[wid * 8 + 1] = m1;                         \
      part[wid * 8 + 2] = m2; part[wid * 8 + 3] = m3;                         \
      part[wid * 8 + 4] = m4;                                                 \
    }                                                                         \
    ldsbar();  /* [2] partials visible (lgkm-only) */                         \
    const float4 pa = *(const float4*)&part[0];                               \
    const float4 pb = *(const float4*)&part[8];                               \
    const float D1 = pa.x + pb.x;                                             \
    const float N0 = pa.y + pb.y;                                             \
    const float D2 = pa.z + pb.z;                                             \
    const float N1 = pa.w + pb.w;                                             \
    const float N2 = part[4] + part[12];                                      \
    const float t1 = D1 * inv128;                                             \
    g0 = fmaf(s1i, N0, s2);                                                   \
    const float gm1 = s1i * (N1 - N0 * t1);                                   \
    const float gm2 = s1i * (0.5f * N2 - (N1 * D1 + 0.5f * N0 * D2) * inv128  \
                             + N0 * t1 * t1);                                 \
    const float hn = fmaf(fmaf(gm2, (arv), gm1), (arv), g0);                  \
    Hb[(size_t)(T) * 128 + tid] = hn;                                         \
    g12 = u2h(pk2(gm1, gm2));                                                 \
    /* ar prefetch (distance-2, after last use) */                            \
    {                                                                         \
      const int tr = ((T) + 2 < TSN) ? (T) + 2 : TSN - 1;                     \
      (arv) = ab[(size_t)tr * 128 + tid];                                     \
    }                                                                         \
  }

  for (int k = 0; k < TSN / 2; ++k) {
    SCAN_STEP(2 * k,     X4e, are, Ae);
    SCAN_STEP(2 * k + 1, X4o, aro, Ao);
  }
#undef SCAN_STEP
}

// ---------------- P3: y = Hall @ W_out^T + b_out -> fp32 (B,C,T) ----------------
__global__ __launch_bounds__(256)
void k_out(const float* __restrict__ W_out, const float* __restrict__ b_out,
           const float* __restrict__ ws, float* __restrict__ out) {
  const int tid = threadIdx.x;
  const int b  = blockIdx.x >> 3;
  const int t0 = (blockIdx.x & 7) * 64;

  // stride 129 (odd): conflict-free read pattern
  __shared__ float Hs[64 * 129];

  const float* Hb = ws + OFF_HALL + ((size_t)b * TSN + t0) * 128;
  for (int k = 0; k < 32; ++k) {
    const int idx = k * 256 + tid;
    Hs[(idx >> 7) * 129 + (idx & 127)] = Hb[idx];
  }
  __syncthreads();

  const int tt = tid & 63;
  const int c0 = (tid >> 6) * 5;
  for (int j = 0; j < 5; ++j) {
    const int c = c0 + j;
    float s = b_out[c];
    for (int i = 0; i < 128; ++i)
      s = fmaf(Hs[tt * 129 + i], W_out[c * 128 + i], s);
    out[((size_t)b * CCN + c) * TSN + t0 + tt] = s;
  }
}

extern "C" void kernel_launch(void* const* d_in, const int* in_sizes, int n_in,
                              void* d_out, int out_size, void* d_ws, size_t ws_size,
                              hipStream_t stream) {
  const float* x    = (const float*)d_in[0];
  const float* W_in = (const float*)d_in[1];
  const float* b_in = (const float*)d_in[2];
  const float* W_out= (const float*)d_in[3];
  const float* b_out= (const float*)d_in[4];
  const float* W_ii = (const float*)d_in[5];
  const float* b_ii = (const float*)d_in[6];
  const float* W_hi = (const float*)d_in[7];
  const float* b_hi = (const float*)d_in[8];
  const float* W_if = (const float*)d_in[9];
  const float* b_if = (const float*)d_in[10];
  const float* W_hf = (const float*)d_in[11];
  const float* b_hf = (const float*)d_in[12];
  const float* W_ig = (const float*)d_in[13];
  const float* b_ig = (const float*)d_in[14];
  const float* W_hg = (const float*)d_in[15];
  const float* b_hg = (const float*)d_in[16];
  const float* W_io = (const float*)d_in[17];
  const float* b_io = (const float*)d_in[18];
  const float* W_ho = (const float*)d_in[19];
  const float* b_ho = (const float*)d_in[20];
  const float* W_xo = (const float*)d_in[21];
  const float* b_xo = (const float*)d_in[22];
  const float* W_q  = (const float*)d_in[23];
  const float* b_q  = (const float*)d_in[24];
  const float* W_k  = (const float*)d_in[25];
  const float* b_k  = (const float*)d_in[26];
  const float* W_v  = (const float*)d_in[27];
  const float* b_v  = (const float*)d_in[28];
  const float* W_ao = (const float*)d_in[29];
  const float* b_ao = (const float*)d_in[30];

  float* ws = (float*)d_ws;
  float* out = (float*)d_out;

  k_prep<<<12, 256, 0, stream>>>(W_in, W_ii, W_if, W_ig, W_io, W_xo, W_q,
                                 W_hi, W_hf, W_hg, W_ho, ws);
  k_xproj<<<512, 128, 0, stream>>>(x, b_in, b_ii, b_hi, b_if, b_hf, b_ig, b_hg,
                                   b_io, b_ho, b_xo, b_q, ws);
  k_scan<<<BB, 128, 0, stream>>>(W_k, b_k, W_v, b_v, W_ao, b_ao, ws);
  k_out<<<BB * 8, 256, 0, stream>>>(W_out, b_out, ws, out);
}

// Round 7
// 457.050 us; speedup vs baseline: 1.5832x; 1.0056x over previous
//
#include <hip/hip_runtime.h>
#include <hip/hip_bf16.h>

// Problem constants
#define BB 8
#define MELN 64
#define TSN 512
#define HHN 128
#define CCN 20

// ws layout (float offsets)
#define OFF_WINT  0                          // W_in^T [64][128]
#define OFF_WT    8192                       // 5x [128][128] transposed f32: ii,if,ig,io,xo
#define OFF_WQ16  (OFF_WT + 5*16384)         // [64][128] u32: pk2(WqT[2p][r], WqT[2p+1][r])
#define OFF_WH16  (OFF_WT + 6*16384)         // [4][64][128] u32: same packing for hi,hf,hg,ho
#define OFF_RS    (OFF_WT + 10*16384)        // [128][4] rowsums of W_hi,W_hf,W_hg,W_ho
#define OFF_XPRE  (OFF_RS + 512)             // [B][T][128 rows][4 gates] x-terms (+both biases) f32
#define OFF_AQ    (OFF_XPRE + BB*TSN*512)    // [B][T][128] a = q/sqrt(H) f32
#define OFF_HALL  (OFF_AQ + BB*TSN*128)      // [B][T][128] h_t f32
#define OFF_APRE  (OFF_HALL + BB*TSN*128)    // [B][T][128] uint4: 4x pk2(A1_g, A2_g) f16
// total floats = OFF_APRE + BB*TSN*128*2 = 5,415,424 (~20.7 MB)

typedef _Float16 hf2 __attribute__((ext_vector_type(2)));

__device__ __forceinline__ float rcp_f(float x) { return __builtin_amdgcn_rcpf(x); }
__device__ __forceinline__ float sigm_f(float x) { return rcp_f(1.0f + __expf(-x)); }
__device__ __forceinline__ float tanh_f(float x) { return fmaf(2.0f, rcp_f(1.0f + __expf(-2.0f * x)), -1.0f); }
__device__ __forceinline__ float sigm_p(float x) { return 1.0f / (1.0f + __expf(-x)); }

#if __has_builtin(__builtin_amdgcn_fdot2)
__device__ __forceinline__ float dot2f(hf2 a, hf2 b, float c) {
  return __builtin_amdgcn_fdot2(a, b, c, false);
}
#else
__device__ __forceinline__ float dot2f(hf2 a, hf2 b, float c) {
  return fmaf((float)a.x, (float)b.x, fmaf((float)a.y, (float)b.y, c));
}
#endif

__device__ __forceinline__ hf2 mk2(float a, float b) {
  hf2 v; v.x = (_Float16)a; v.y = (_Float16)b; return v;
}
__device__ __forceinline__ unsigned pk2(float a, float b) {
  return __builtin_bit_cast(unsigned, __builtin_amdgcn_cvt_pkrtz(a, b));
}
__device__ __forceinline__ unsigned mku(float a, float b) {
  return __builtin_bit_cast(unsigned, mk2(a, b));   // RTE pack (2x cvt)
}
__device__ __forceinline__ hf2 u2h(unsigned u) { return __builtin_bit_cast(hf2, u); }

// ---- wave-64 sum: DPP (VALU-pipe) with shfl fallback. Result valid in lane 63. ----
#if __has_builtin(__builtin_amdgcn_update_dpp)
template <int CTRL>
__device__ __forceinline__ float dppadd(float x) {
  int v = __builtin_amdgcn_update_dpp(0, __builtin_bit_cast(int, x), CTRL, 0xf, 0xf, true);
  return x + __builtin_bit_cast(float, v);
}
__device__ __forceinline__ float wsum64(float x) {
  x = dppadd<0x111>(x);   // row_shr:1
  x = dppadd<0x112>(x);   // row_shr:2
  x = dppadd<0x114>(x);   // row_shr:4
  x = dppadd<0x118>(x);   // row_shr:8  -> lane15 of each 16-row has row sum
  x = dppadd<0x142>(x);   // row_bcast:15 -> lane31/63 have 32-lane sums
  x = dppadd<0x143>(x);   // row_bcast:31 -> lane63 has 64-lane sum
  return x;
}
#else
__device__ __forceinline__ float wsum64(float x) {
  x += __shfl_xor(x, 1);  x += __shfl_xor(x, 2);  x += __shfl_xor(x, 4);
  x += __shfl_xor(x, 8);  x += __shfl_xor(x, 16); x += __shfl_xor(x, 32);
  return x;
}
#endif

// ---- lgkm-only workgroup barrier: does NOT drain vmcnt, so in-flight global
// prefetch loads survive across it. sched_barrier(0) pins LDS ops (rule #18).
__device__ __forceinline__ void ldsbar() {
  __builtin_amdgcn_sched_barrier(0);
  asm volatile("s_waitcnt lgkmcnt(0)" ::: "memory");
  __builtin_amdgcn_s_barrier();
  __builtin_amdgcn_sched_barrier(0);
}

// ---------------- P0: weight prep ----------------
// m==0: W_in transpose. m 1..5: transpose ii,if,ig,io,xo (f32).
// m==6: W_q -> f16-pair pack. m 7..10: W_hi..W_ho -> f16-pair pack. m==11: rowsums.
__global__ void k_prep(const float* __restrict__ W_in, const float* __restrict__ W_ii,
                       const float* __restrict__ W_if, const float* __restrict__ W_ig,
                       const float* __restrict__ W_io, const float* __restrict__ W_xo,
                       const float* __restrict__ W_q,  const float* __restrict__ W_hi,
                       const float* __restrict__ W_hf, const float* __restrict__ W_hg,
                       const float* __restrict__ W_ho, float* __restrict__ ws) {
  int m = blockIdx.x;  // 0..11
  if (m == 11) {
    for (int idx = threadIdx.x; idx < 512; idx += blockDim.x) {
      int g = idx >> 7, r = idx & 127;
      const float* W = (g == 0) ? W_hi : (g == 1) ? W_hf : (g == 2) ? W_hg : W_ho;
      float s = 0.f;
      for (int c = 0; c < 128; ++c) s += W[r * 128 + c];
      ws[OFF_RS + r * 4 + g] = s;
    }
    return;
  }
  if (m == 0) {
    for (int idx = threadIdx.x; idx < 128 * 64; idx += blockDim.x) {
      int r = idx >> 6, c = idx & 63;
      ws[OFF_WINT + c * 128 + r] = W_in[idx];
    }
    return;
  }
  const float* s[10] = {W_ii, W_if, W_ig, W_io, W_xo, W_q, W_hi, W_hf, W_hg, W_ho};
  const float* src = s[m - 1];
  if (m <= 5) {   // f32 transpose: dst[c][r] = W[r][c]
    float* dst = ws + OFF_WT + (size_t)(m - 1) * 16384;
    for (int idx = threadIdx.x; idx < 16384; idx += blockDim.x) {
      int r = idx >> 7, c = idx & 127;
      dst[c * 128 + r] = src[idx];
    }
  } else {        // f16-pair pack along the contraction axis: dst[p][r] = (W[r][2p], W[r][2p+1])
    unsigned* dst = (m == 6)
        ? (unsigned*)(ws + OFF_WQ16)
        : (unsigned*)(ws + OFF_WH16) + (size_t)(m - 7) * 8192;
    for (int idx = threadIdx.x; idx < 8192; idx += blockDim.x) {
      int p = idx >> 7, r = idx & 127;
      dst[p * 128 + r] = mku(src[r * 128 + 2 * p], src[r * 128 + 2 * p + 1]);
    }
  }
}

// ---------------- P1: x-side projections + A-moment precompute.
// 4 t's per block, 1024 blocks -> 4 blocks/CU (8 waves/CU) for latency hiding
// (previous 8t/512blk ran at 1 wave/SIMD: every chain edge + L2 load exposed).
// Gate x-terms full f32; q-projection and A-moments in f16-pair dot2. ----
__global__ __launch_bounds__(128)
void k_xproj(const float* __restrict__ x,
             const float* __restrict__ b_in,
             const float* __restrict__ b_ii, const float* __restrict__ b_hi,
             const float* __restrict__ b_if, const float* __restrict__ b_hf,
             const float* __restrict__ b_ig, const float* __restrict__ b_hg,
             const float* __restrict__ b_io, const float* __restrict__ b_ho,
             const float* __restrict__ b_xo, const float* __restrict__ b_q,
             float* __restrict__ ws) {
  const int tid = threadIdx.x;
  const int b  = blockIdx.x >> 7;            // 0..7
  const int t0 = (blockIdx.x & 127) * 4;     // 0..508

  __shared__ __align__(16) float xsT[MELN * 4];     // [m][tt]
  __shared__ __align__(16) float xpsT[128 * 4];     // [c][tt]  (xp, then a)
  __shared__ __align__(16) float xosT[128 * 4];     // [c][tt]  (x_o)
  __shared__ __align__(16) unsigned xo16[64 * 4];   // [p][tt] f16 pairs of sigma(xo)
  __shared__ __align__(16) unsigned ap16[64 * 4];   // [p][tt] f16 pairs of a
  __shared__ __align__(16) unsigned as16[64 * 4];   // [p][tt] f16 pairs of a^2

  const float* WinT = ws + OFF_WINT;
  const float* WT   = ws + OFF_WT;
  float* Xpre = ws + OFF_XPRE;
  float* aq   = ws + OFF_AQ;

  // stage x: 64 rows x 4 t's = 256 elems, 2 per thread
  #pragma unroll
  for (int k = 0; k < 2; ++k) {
    int idx = k * 128 + tid;
    int mm = idx >> 2, tt = idx & 3;
    xsT[mm * 4 + tt] = x[((size_t)b * MELN + mm) * TSN + t0 + tt];
  }
  __syncthreads();

  // xp rows: thread = output feature
  float acc4[4];
  {
    float bi = b_in[tid];
    #pragma unroll
    for (int j = 0; j < 4; ++j) acc4[j] = bi;
  }
  #pragma unroll 2
  for (int mI = 0; mI < MELN; ++mI) {
    float w = WinT[mI * 128 + tid];
    float4 xa = *(const float4*)&xsT[mI * 4];
    acc4[0] = fmaf(w, xa.x, acc4[0]); acc4[1] = fmaf(w, xa.y, acc4[1]);
    acc4[2] = fmaf(w, xa.z, acc4[2]); acc4[3] = fmaf(w, xa.w, acc4[3]);
  }
  *(float4*)&xpsT[tid * 4] = make_float4(acc4[0], acc4[1], acc4[2], acc4[3]);
  __syncthreads();

  // gate x-terms (ii,if,ig,io) + xo — full f32
  float accg[5][4];
  {
    float bsum[5];
    bsum[0] = b_ii[tid] + b_hi[tid];
    bsum[1] = b_if[tid] + b_hf[tid];
    bsum[2] = b_ig[tid] + b_hg[tid];
    bsum[3] = b_io[tid] + b_ho[tid];
    bsum[4] = b_xo[tid];
    #pragma unroll
    for (int g = 0; g < 5; ++g)
      #pragma unroll
      for (int j = 0; j < 4; ++j) accg[g][j] = bsum[g];
  }
  #pragma unroll 2
  for (int c = 0; c < 128; ++c) {
    const float4 xa = *(const float4*)&xpsT[c * 4];
    #pragma unroll
    for (int g = 0; g < 5; ++g) {
      const float w = WT[g * 16384 + c * 128 + tid];
      accg[g][0] = fmaf(w, xa.x, accg[g][0]);
      accg[g][1] = fmaf(w, xa.y, accg[g][1]);
      accg[g][2] = fmaf(w, xa.z, accg[g][2]);
      accg[g][3] = fmaf(w, xa.w, accg[g][3]);
    }
  }
  {
    size_t base = ((size_t)b * TSN + t0) * 512;
    #pragma unroll
    for (int tt = 0; tt < 4; ++tt)
      *(float4*)&Xpre[base + (size_t)tt * 512 + tid * 4] =
          make_float4(accg[0][tt], accg[1][tt], accg[2][tt], accg[3][tt]);
  }
  {
    #pragma unroll
    for (int tt = 0; tt < 4; ++tt) xosT[tid * 4 + tt] = sigm_p(accg[4][tt]);
  }
  __syncthreads();

  // pack sigma(xo) into f16 pairs along c: 64 p x 4 tt, 2 per thread
  {
    const int p = tid & 63;
    const int th = (tid >> 6) * 2;
    #pragma unroll
    for (int j = 0; j < 2; ++j) {
      const int tt = th + j;
      xo16[p * 4 + tt] = mku(xosT[(2 * p) * 4 + tt], xosT[(2 * p + 1) * 4 + tt]);
    }
  }
  __syncthreads();

  // q projection on x_o (f16 dot2) -> a = q / sqrt(H)
  float accq[4];
  {
    float bq = b_q[tid];
    #pragma unroll
    for (int j = 0; j < 4; ++j) accq[j] = bq;
  }
  const unsigned* WQ = (const unsigned*)(ws + OFF_WQ16);
  #pragma unroll 2
  for (int p = 0; p < 64; ++p) {
    const hf2 wq = u2h(WQ[p * 128 + tid]);
    const uint4 xa = *(const uint4*)&xo16[p * 4];
    accq[0] = dot2f(wq, u2h(xa.x), accq[0]);
    accq[1] = dot2f(wq, u2h(xa.y), accq[1]);
    accq[2] = dot2f(wq, u2h(xa.z), accq[2]);
    accq[3] = dot2f(wq, u2h(xa.w), accq[3]);
  }
  float av[4];
  #pragma unroll
  for (int tt = 0; tt < 4; ++tt) {
    av[tt] = accq[tt] * 0.08838834764831845f;
    aq[((size_t)b * TSN + t0 + tt) * 128 + tid] = av[tt];
  }

  // ---- A-moments (f16 dot2): A1 = W@a, A2 = W@a^2 for 4 gate matrices ----
  __syncthreads();   // gate/q phases' LDS reads complete
  *(float4*)&xpsT[tid * 4] = make_float4(av[0], av[1], av[2], av[3]);
  __syncthreads();
  {
    const int p = tid & 63;
    const int th = (tid >> 6) * 2;
    #pragma unroll
    for (int j = 0; j < 2; ++j) {
      const int tt = th + j;
      const float a0 = xpsT[(2 * p) * 4 + tt];
      const float a1 = xpsT[(2 * p + 1) * 4 + tt];
      ap16[p * 4 + tt] = mku(a0, a1);
      as16[p * 4 + tt] = mku(a0 * a0, a1 * a1);
    }
  }
  __syncthreads();
  float accA[4][4], accB[4][4];
  #pragma unroll
  for (int g = 0; g < 4; ++g)
    #pragma unroll
    for (int j = 0; j < 4; ++j) { accA[g][j] = 0.f; accB[g][j] = 0.f; }
  const unsigned* WH = (const unsigned*)(ws + OFF_WH16);
  #pragma unroll 2
  for (int p = 0; p < 64; ++p) {
    const uint4 aa = *(const uint4*)&ap16[p * 4];
    const uint4 sa = *(const uint4*)&as16[p * 4];
    #pragma unroll
    for (int g = 0; g < 4; ++g) {
      const hf2 w = u2h(WH[g * 8192 + p * 128 + tid]);
      accA[g][0] = dot2f(w, u2h(aa.x), accA[g][0]);
      accA[g][1] = dot2f(w, u2h(aa.y), accA[g][1]);
      accA[g][2] = dot2f(w, u2h(aa.z), accA[g][2]);
      accA[g][3] = dot2f(w, u2h(aa.w), accA[g][3]);
      accB[g][0] = dot2f(w, u2h(sa.x), accB[g][0]);
      accB[g][1] = dot2f(w, u2h(sa.y), accB[g][1]);
      accB[g][2] = dot2f(w, u2h(sa.z), accB[g][2]);
      accB[g][3] = dot2f(w, u2h(sa.w), accB[g][3]);
    }
  }
  {
    uint4* APre4 = (uint4*)(ws + OFF_APRE);
    #pragma unroll
    for (int tt = 0; tt < 4; ++tt) {
      uint4 u;
      u.x = pk2(accA[0][tt], accB[0][tt]);
      u.y = pk2(accA[1][tt], accB[1][tt]);
      u.z = pk2(accA[2][tt], accB[2][tt]);
      u.w = pk2(accA[3][tt], accB[3][tt]);
      APre4[((size_t)b * TSN + t0 + tt) * 128 + tid] = u;
    }
  }
}

// ---------------- P2: scan. 128 thr (2 waves); DPP reduce + distance-2 register prefetch.
// Barriers are lgkm-only (ldsbar) so prefetch global loads stay in flight across them. ----
__global__ __launch_bounds__(128, 1)
void k_scan(const float* __restrict__ W_k,  const float* __restrict__ b_k,
            const float* __restrict__ W_v,  const float* __restrict__ b_v,
            const float* __restrict__ W_ao, const float* __restrict__ b_ao,
            float* __restrict__ ws) {
  const int tid  = threadIdx.x;    // row 0..127
  const int lane = tid & 63;
  const int wid  = tid >> 6;       // wave 0..1
  const int b    = blockIdx.x;

  __shared__ __align__(16) _Float16 ch[128];     // c as f16 (direct b16 stores)
  __shared__ __align__(16) float part[16];       // [wave][moment 0..4] (stride 8)

  // full W_k row in registers as 64 f16 pairs (64 VGPRs)
  hf2 wkk2[64];
  #pragma unroll
  for (int p = 0; p < 64; ++p)
    wkk2[p] = mk2(W_k[(size_t)tid * 128 + 2 * p], W_k[(size_t)tid * 128 + 2 * p + 1]);
  const float bkr = b_k[tid];
  const float4 RSv = *(const float4*)&ws[OFF_RS + tid * 4];   // rowsums (ii,if,ig,io)

  // collapsed attention-output constants: h = s1*(attn.o) + s2
  float s1 = 0.f, s2 = 0.f;
  for (int j = 0; j < 128; ++j) {
    s1 = fmaf(W_ao[j], W_v[j], s1);
    s2 = fmaf(W_ao[j], b_v[j], s2);
  }
  s2 += b_ao[0];
  const float inv128 = 0.0078125f;
  const float s1i = s1 * inv128;

  const float* Xb = ws + OFF_XPRE + (size_t)b * TSN * 512;
  const float* ab = ws + OFF_AQ   + (size_t)b * TSN * 128;
  float*       Hb = ws + OFF_HALL + (size_t)b * TSN * 128;
  const uint4* APb = (const uint4*)(ws + OFF_APRE) + (size_t)b * TSN * 128;

  const uint4* c4u = (const uint4*)ch;

  // even/odd register sets (distance-2 prefetch; static names per rule #20)
  float4 X4e = *(const float4*)&Xb[tid * 4];                    // t=0
  float4 X4o = *(const float4*)&Xb[512 + tid * 4];              // t=1
  float  are = ab[tid];                                         // t=0
  float  aro = ab[128 + tid];                                   // t=1
  uint4  Ae  = APb[tid];   // dummy finite (t=0 has gamma=0)
  uint4  Ao  = APb[tid];   // A slot 0, used at t=1

  float c_reg = 0.f;
  float g0 = 0.f;                  // gamma0
  hf2   g12 = u2h(0u);             // (gamma1, gamma2) packed f16

#define SCAN_STEP(T, X4v, arv, Argv)                                          \
  {                                                                           \
    const float pi = dot2f(u2h((Argv).x), g12, fmaf(g0, RSv.x, (X4v).x));     \
    const float pf = dot2f(u2h((Argv).y), g12, fmaf(g0, RSv.y, (X4v).y));     \
    const float pg = dot2f(u2h((Argv).z), g12, fmaf(g0, RSv.z, (X4v).z));     \
    const float po = dot2f(u2h((Argv).w), g12, fmaf(g0, RSv.w, (X4v).w));     \
    /* early prefetch into this parity's regs (X,A last used above) */        \
    {                                                                         \
      const int tx = ((T) + 2 < TSN) ? (T) + 2 : TSN - 1;                     \
      (X4v) = *(const float4*)&Xb[(size_t)tx * 512 + tid * 4];                \
      const int ta = ((T) + 1 < TSN) ? (T) + 1 : TSN - 1;                     \
      (Argv) = APb[(size_t)ta * 128 + tid];                                   \
    }                                                                         \
    const float gi = sigm_f(pi);                                              \
    const float gf = sigm_f(pf);                                              \
    const float gg = tanh_f(pg);                                              \
    const float go = sigm_f(po);                                              \
    c_reg = fmaf(gf, c_reg, gi * gg);                                         \
    ch[tid] = (_Float16)c_reg;                                                \
    ldsbar();  /* [1] c visible (lgkm-only) */                                \
    float ka0 = 0.f, ka1 = 0.f, ka2 = 0.f, ka3 = 0.f;                         \
    _Pragma("unroll")                                                         \
    for (int u = 0; u < 16; ++u) {                                            \
      const uint4 cv = c4u[u];                                                \
      ka0 = dot2f(wkk2[u * 4 + 0], u2h(cv.x), ka0);                           \
      ka1 = dot2f(wkk2[u * 4 + 1], u2h(cv.y), ka1);                           \
      ka2 = dot2f(wkk2[u * 4 + 2], u2h(cv.z), ka2);                           \
      ka3 = dot2f(wkk2[u * 4 + 3], u2h(cv.w), ka3);                           \
    }                                                                         \
    const float kr = ((ka0 + ka1) + (ka2 + ka3)) + bkr;                       \
    const float kp2 = kr * kr;                                                \
    float m0 = kr, m1 = go, m2 = kp2, m3 = go * kr, m4 = go * kp2;            \
    m0 = wsum64(m0); m1 = wsum64(m1); m2 = wsum64(m2);                        \
    m3 = wsum64(m3); m4 = wsum64(m4);                                         \
    if (lane == 63) {                                                         \
      part[wid * 8 + 0] = m0; part[wid * 8 + 1] = m1;                         \
      part[wid * 8 + 2] = m2; part[wid * 8 + 3] = m3;                         \
      part[wid * 8 + 4] = m4;                                                 \
    }                                                                         \
    ldsbar();  /* [2] partials visible (lgkm-only) */                         \
    const float4 pa = *(const float4*)&part[0];                               \
    const float4 pb = *(const float4*)&part[8];                               \
    const float D1 = pa.x + pb.x;                                             \
    const float N0 = pa.y + pb.y;                                             \
    const float D2 = pa.z + pb.z;                                             \
    const float N1 = pa.w + pb.w;                                             \
    const float N2 = part[4] + part[12];                                      \
    const float t1 = D1 * inv128;                                             \
    g0 = fmaf(s1i, N0, s2);                                                   \
    const float gm1 = s1i * (N1 - N0 * t1);                                   \
    const float gm2 = s1i * (0.5f * N2 - (N1 * D1 + 0.5f * N0 * D2) * inv128  \
                             + N0 * t1 * t1);                                 \
    const float hn = fmaf(fmaf(gm2, (arv), gm1), (arv), g0);                  \
    Hb[(size_t)(T) * 128 + tid] = hn;                                         \
    g12 = u2h(pk2(gm1, gm2));                                                 \
    /* ar prefetch (distance-2, after last use) */                            \
    {                                                                         \
      const int tr = ((T) + 2 < TSN) ? (T) + 2 : TSN - 1;                     \
      (arv) = ab[(size_t)tr * 128 + tid];                                     \
    }                                                                         \
  }

  for (int k = 0; k < TSN / 2; ++k) {
    SCAN_STEP(2 * k,     X4e, are, Ae);
    SCAN_STEP(2 * k + 1, X4o, aro, Ao);
  }
#undef SCAN_STEP
}

// ---------------- P3: y = Hall @ W_out^T + b_out -> fp32 (B,C,T) ----------------
__global__ __launch_bounds__(256)
void k_out(const float* __restrict__ W_out, const float* __restrict__ b_out,
           const float* __restrict__ ws, float* __restrict__ out) {
  const int tid = threadIdx.x;
  const int b  = blockIdx.x >> 3;
  const int t0 = (blockIdx.x & 7) * 64;

  // stride 129 (odd): conflict-free read pattern
  __shared__ float Hs[64 * 129];

  const float* Hb = ws + OFF_HALL + ((size_t)b * TSN + t0) * 128;
  for (int k = 0; k < 32; ++k) {
    const int idx = k * 256 + tid;
    Hs[(idx >> 7) * 129 + (idx & 127)] = Hb[idx];
  }
  __syncthreads();

  const int tt = tid & 63;
  const int c0 = (tid >> 6) * 5;
  for (int j = 0; j < 5; ++j) {
    const int c = c0 + j;
    float s = b_out[c];
    for (int i = 0; i < 128; ++i)
      s = fmaf(Hs[tt * 129 + i], W_out[c * 128 + i], s);
    out[((size_t)b * CCN + c) * TSN + t0 + tt] = s;
  }
}

extern "C" void kernel_launch(void* const* d_in, const int* in_sizes, int n_in,
                              void* d_out, int out_size, void* d_ws, size_t ws_size,
                              hipStream_t stream) {
  const float* x    = (const float*)d_in[0];
  const float* W_in = (const float*)d_in[1];
  const float* b_in = (const float*)d_in[2];
  const float* W_out= (const float*)d_in[3];
  const float* b_out= (const float*)d_in[4];
  const float* W_ii = (const float*)d_in[5];
  const float* b_ii = (const float*)d_in[6];
  const float* W_hi = (const float*)d_in[7];
  const float* b_hi = (const float*)d_in[8];
  const float* W_if = (const float*)d_in[9];
  const float* b_if = (const float*)d_in[10];
  const float* W_hf = (const float*)d_in[11];
  const float* b_hf = (const float*)d_in[12];
  const float* W_ig = (const float*)d_in[13];
  const float* b_ig = (const float*)d_in[14];
  const float* W_hg = (const float*)d_in[15];
  const float* b_hg = (const float*)d_in[16];
  const float* W_io = (const float*)d_in[17];
  const float* b_io = (const float*)d_in[18];
  const float* W_ho = (const float*)d_in[19];
  const float* b_ho = (const float*)d_in[20];
  const float* W_xo = (const float*)d_in[21];
  const float* b_xo = (const float*)d_in[22];
  const float* W_q  = (const float*)d_in[23];
  const float* b_q  = (const float*)d_in[24];
  const float* W_k  = (const float*)d_in[25];
  const float* b_k  = (const float*)d_in[26];
  const float* W_v  = (const float*)d_in[27];
  const float* b_v  = (const float*)d_in[28];
  const float* W_ao = (const float*)d_in[29];
  const float* b_ao = (const float*)d_in[30];

  float* ws = (float*)d_ws;
  float* out = (float*)d_out;

  k_prep<<<12, 256, 0, stream>>>(W_in, W_ii, W_if, W_ig, W_io, W_xo, W_q,
                                 W_hi, W_hf, W_hg, W_ho, ws);
  k_xproj<<<BB * 128, 128, 0, stream>>>(x, b_in, b_ii, b_hi, b_if, b_hf, b_ig, b_hg,
                                        b_io, b_ho, b_xo, b_q, ws);
  k_scan<<<BB, 128, 0, stream>>>(W_k, b_k, W_v, b_v, W_ao, b_ao, ws);
  k_out<<<BB * 8, 256, 0, stream>>>(W_out, b_out, ws, out);
}